// Round 9
// baseline (451.310 us; speedup 1.0000x reference)
//
#include <hip/hip_runtime.h>

// ---------------------------------------------------------------------------
// Attention_16698832847178: B=2,S=2048,D=2048,H=16,HD=128,L=10
// R14: (1) kloop staging depth fix: all 6 slots of t+1 issued at p0 into the
// opposite buffer (race-free by t-1's trailing barrier), vmcnt(0) at p1-end
// -> every load gets ~2 phases (~460cyc) cover vs 1.5 phases before.
// (2) flash: setprio around QK/PV MFMA clusters (T5). (3) adapter_pack
// dispatch removed: flash epilogue reads ak/av fp32 directly with inline
// l>=10 masking. prep/flash-dbuf/gemm geometry unchanged from R13.
// ---------------------------------------------------------------------------

typedef unsigned short ushort_t;
typedef unsigned int uint32;
typedef __attribute__((ext_vector_type(8))) short bf16x8;   // 8 bf16 = 4 VGPRs
typedef __attribute__((ext_vector_type(4))) float f32x4;

__device__ __forceinline__ void async16(void* lds, const void* g) {
  __builtin_amdgcn_global_load_lds((const __attribute__((address_space(1))) void*)g,
                                   (__attribute__((address_space(3))) void*)lds,
                                   16, 0, 0);
}
__device__ __forceinline__ ushort_t f2bf(float f) {
  uint32 u = __float_as_uint(f);
  u += 0x7FFFu + ((u >> 16) & 1u);   // round-to-nearest-even
  return (ushort_t)(u >> 16);
}
__device__ __forceinline__ float bf2f(ushort_t b) {
  return __uint_as_float(((uint32)b) << 16);
}
// value from lane^1 via DPP quad_perm [1,0,3,2] (VALU, no LDS)
__device__ __forceinline__ float dpp_xor1(float v) {
  return __int_as_float(__builtin_amdgcn_update_dpp(
      0, __float_as_int(v), 0xB1, 0xf, 0xf, true));
}
#define DPP_MAX(t, ctrl) \
  t = fmaxf(t, __int_as_float(__builtin_amdgcn_update_dpp( \
      0, __float_as_int(t), (ctrl), 0xf, 0xf, true)))
#define DPP_ADD(t, ctrl) \
  t += __int_as_float(__builtin_amdgcn_update_dpp( \
      0, __float_as_int(t), (ctrl), 0xf, 0xf, true))
__device__ __forceinline__ float rowmax16(float t) {
  DPP_MAX(t, 0xB1);   // xor 1
  DPP_MAX(t, 0x4E);   // xor 2
  t = fmaxf(t, __int_as_float(__builtin_amdgcn_ds_swizzle(
      __float_as_int(t), 0x101F)));                  // xor 4
  DPP_MAX(t, 0x128);  // row_ror:8 -> xor 8 (halves uniform after xor1/2/4)
  return t;
}
__device__ __forceinline__ float rowsum16(float t) {
  DPP_ADD(t, 0xB1);
  DPP_ADD(t, 0x4E);
  t += __int_as_float(__builtin_amdgcn_ds_swizzle(__float_as_int(t), 0x101F));
  DPP_ADD(t, 0x128);
  return t;
}

// ---------------------------------------------------------------------------
// Merged preprocessing: [0,4096) cast x->bf16; [4096,8192) transpose W;
// [8192,8448) adapter projections (atomic, 256-block layout as before).
__global__ __launch_bounds__(256) void prep_kernel(
    const float* __restrict__ x, ushort_t* __restrict__ Xb,
    const float* __restrict__ w0, const float* __restrict__ w1,
    const float* __restrict__ w2, const float* __restrict__ w3,
    ushort_t* __restrict__ WtBase,
    const float* __restrict__ adapter,
    float* __restrict__ ak, float* __restrict__ av) {
  __shared__ float L[64][65];
  const int bid = (int)blockIdx.x;
  const int t = (int)threadIdx.x;

  if (bid < 4096) {
    // ---- cast x (fp32) -> bf16, 8 elements/thread ----
    size_t i = ((size_t)bid * 256 + t) * 8;
    float4 a = *(const float4*)(x + i);
    float4 b = *(const float4*)(x + i + 4);
    uint4 o;
    o.x = (uint32)f2bf(a.x) | ((uint32)f2bf(a.y) << 16);
    o.y = (uint32)f2bf(a.z) | ((uint32)f2bf(a.w) << 16);
    o.z = (uint32)f2bf(b.x) | ((uint32)f2bf(b.y) << 16);
    o.w = (uint32)f2bf(b.z) | ((uint32)f2bf(b.w) << 16);
    *(uint4*)(Xb + i) = o;
    return;
  }
  if (bid < 8192) {
    // ---- W[k][n] fp32 -> Wt[n][k] bf16 (64x64 tiles) ----
    int c = bid - 4096;
    const int z = c >> 10, rem = c & 1023;
    const int bx = rem & 31, by = rem >> 5;
    const float* W = (z == 0) ? w0 : (z == 1) ? w1 : (z == 2) ? w2 : w3;
    ushort_t* Wt = WtBase + (size_t)z * 4194304;  // 2048*2048
    int tc = t & 63, tr = t >> 6;
    int k0 = bx * 64, n0 = by * 64;
    for (int i = 0; i < 16; ++i) {
      int r = i * 4 + tr;
      L[r][tc] = W[(size_t)(k0 + r) * 2048 + n0 + tc];
    }
    __syncthreads();
    int tr8 = t >> 5, tc2 = t & 31;
    for (int i = 0; i < 8; ++i) {
      int r = i * 8 + tr8;
      uint32 pk = (uint32)f2bf(L[2 * tc2][r]) | ((uint32)f2bf(L[2 * tc2 + 1][r]) << 16);
      *(uint32*)(Wt + (size_t)(n0 + r) * 2048 + k0 + 2 * tc2) = pk;
    }
    return;
  }
  {
    // ---- adapter: ak/av[l][n] = sum_k adapter[l][k] * W[k][n] ----
    int c = bid - 8192;               // [0,256)
    const int z = c >> 7;             // 0=wk, 1=wv
    const int ky = (c >> 3) & 15;     // k-chunk
    const int xx = c & 7;             // n-chunk
    const float* W = z ? w2 : w1;     // wv : wk
    float* out = z ? av : ak;
    float (*As)[128] = (float(*)[128])L;
    int k0 = ky * 128;
    for (int i = t; i < 1280; i += 256)
      As[i >> 7][i & 127] = adapter[(size_t)(i >> 7) * 2048 + k0 + (i & 127)];
    __syncthreads();
    int n = xx * 256 + t;
    float acc[10];
#pragma unroll
    for (int l = 0; l < 10; ++l) acc[l] = 0.f;
    for (int kk = 0; kk < 128; ++kk) {
      float wv_ = W[(size_t)(k0 + kk) * 2048 + n];
#pragma unroll
      for (int l = 0; l < 10; ++l) acc[l] += As[l][kk] * wv_;
    }
#pragma unroll
    for (int l = 0; l < 10; ++l) atomicAdd(&out[l * 2048 + n], acc[l]);
  }
}

#define QK_BARX() asm volatile("s_barrier" ::: "memory")
#define QK_LGKM0() asm volatile("s_waitcnt lgkmcnt(0)" ::: "memory")

// ---------------------------------------------------------------------------
// Pipelined 128x256 K-loop (A and B in LDS), R14 deep staging:
// all 6 slots of t+1 issued at p0 (opposite buffer, retired at t-1's end
// barrier -> race-free); vmcnt(0) at p1-end gives every load ~2 phases of
// latency cover (was 1.5 phases for A/B0 under the old vmcnt(3) scheme).
__device__ __forceinline__ void kloop_128x256(
    char* lds, const ushort_t* __restrict__ A, const ushort_t* __restrict__ Bt,
    size_t bm0, size_t bn0, f32x4 (&acc)[4][4]) {
  const int tid = (int)threadIdx.x;
  const int w = tid >> 6, lane = tid & 63, quad = lane >> 4, l15 = lane & 15;
  const int wr = (w >> 2) * 64, wc = (w & 3) * 64;
  const int nt = 32;
  char* const pA0 = lds;
  char* const pA1 = lds + 16384;
  char* const pB0 = lds + 32768;
  char* const pB1 = lds + 65536;

#define PAT(T) (((T) & 1) ? pA1 : pA0)
#define PBT(T) (((T) & 1) ? pB1 : pB0)
#define SEGL(OP, LDSB, GROW, T)                                                \
  do {                                                                         \
    int rr_ = w * 8 + (lane >> 3);                                             \
    int cl_ = (lane & 7) ^ (rr_ & 7);                                          \
    async16((LDSB) + w * 1024,                                                 \
            (OP) + ((GROW) + (size_t)rr_) * 2048 + (size_t)((T) * 64 + cl_ * 8)); \
  } while (0)
// all 6 slots of tile T (A 2 + B 4), opposite-buffer only
#define ST_ALL(T)                                                              \
  do { if ((T) < nt) {                                                         \
    SEGL(A, PAT(T), bm0, (T));                                                 \
    SEGL(A, PAT(T) + 8192, bm0 + 64, (T));                                     \
    SEGL(Bt, PBT(T), bn0, (T));                                                \
    SEGL(Bt, PBT(T) + 8192,  bn0 + 64,  (T));                                  \
    SEGL(Bt, PBT(T) + 16384, bn0 + 128, (T));                                  \
    SEGL(Bt, PBT(T) + 24576, bn0 + 192, (T));                                  \
  } } while (0)

  ST_ALL(0);
  asm volatile("s_waitcnt vmcnt(0)" ::: "memory");
  QK_BARX();

#pragma unroll 2
  for (int t = 0; t < nt; ++t) {
    const char* pA = PAT(t);
    const char* pB = PBT(t);
    bf16x8 bfv[4][2];
#pragma unroll
    for (int j = 0; j < 4; ++j) {
      int brow = wc + j * 16 + l15;
#pragma unroll
      for (int ks = 0; ks < 2; ++ks)
        bfv[j][ks] = *(const bf16x8*)(pB + brow * 128 +
                                      (((ks * 4 + quad) ^ (brow & 7)) * 16));
    }
#pragma unroll
    for (int ph = 0; ph < 2; ++ph) {
      bf16x8 af[2][2];
#pragma unroll
      for (int ii = 0; ii < 2; ++ii) {
        int arow = wr + (ph * 2 + ii) * 16 + l15;
#pragma unroll
        for (int ks = 0; ks < 2; ++ks)
          af[ii][ks] = *(const bf16x8*)(pA + arow * 128 +
                                        (((ks * 4 + quad) ^ (arow & 7)) * 16));
      }
      if (ph == 0) ST_ALL(t + 1);
      QK_BARX();
      QK_LGKM0();
      __builtin_amdgcn_s_setprio(1);
#pragma unroll
      for (int ks = 0; ks < 2; ++ks)
#pragma unroll
        for (int ii = 0; ii < 2; ++ii)
#pragma unroll
          for (int j = 0; j < 4; ++j)
            acc[ph * 2 + ii][j] = __builtin_amdgcn_mfma_f32_16x16x32_bf16(
                af[ii][ks], bfv[j][ks], acc[ph * 2 + ii][j], 0, 0, 0);
      __builtin_amdgcn_s_setprio(0);
      if (ph == 1) asm volatile("s_waitcnt vmcnt(0)" ::: "memory");
      QK_BARX();
    }
  }
#undef PAT
#undef PBT
#undef SEGL
#undef ST_ALL
}

// ---------------------------------------------------------------------------
// Fused QKV GEMM: C[4096,6144] = Xb[4096,2048] x WtQKV[6144,2048]^T.
// Grid 768 (32 M x 24 N) = exactly 3 rounds of 256 CUs.
__global__ __launch_bounds__(512, 2) void gemm_qkv128_kernel(
    const ushort_t* __restrict__ A, const ushort_t* __restrict__ Bt,
    ushort_t* __restrict__ outQ, ushort_t* __restrict__ outK,
    ushort_t* __restrict__ Vt,
    const float* __restrict__ fc, const float* __restrict__ fs) {
  __shared__ char lds[98304];
  const int tid = (int)threadIdx.x;
  const int w = tid >> 6, lane = tid & 63, quad = lane >> 4, l15 = lane & 15;
  const int wr = (w >> 2) * 64, wc = (w & 3) * 64;

  const int wg = ((int)blockIdx.x & 7) * 96 + ((int)blockIdx.x >> 3);
  const size_t bm0 = (size_t)(wg & 31) * 128;
  const size_t bn0 = (size_t)(wg >> 5) * 256;

  f32x4 acc[4][4];
  f32x4 z4 = {0.f, 0.f, 0.f, 0.f};
#pragma unroll
  for (int i = 0; i < 4; ++i)
#pragma unroll
    for (int j = 0; j < 4; ++j) acc[i][j] = z4;

  kloop_128x256(lds, A, Bt, bm0, bn0, acc);

  const int seg = (int)(bn0 >> 11);   // 0=Q, 1=K, 2=V
  if (seg < 2) {
    ushort_t* ob = seg ? outK : outQ;
#pragma unroll
    for (int i = 0; i < 4; ++i)
#pragma unroll
      for (int r = 0; r < 4; ++r) {
        size_t m = bm0 + wr + i * 16 + quad * 4 + r;
        int s = (int)(m & 2047);
#pragma unroll
        for (int j = 0; j < 4; ++j) {
          size_t n = (bn0 + wc + j * 16 + l15) & 2047;
          float v = acc[i][j][r];
          float v2 = dpp_xor1(v);             // RoPE pair partner (col n^1)
          int fi = ((int)n & 127) >> 1;
          float cosv = fc[s * 64 + fi];
          float sinv = fs[s * 64 + fi];
          v = (lane & 1) ? (v2 * sinv + v * cosv) : (v * cosv - v2 * sinv);
          ob[m * 2048 + n] = f2bf(v);
        }
      }
  } else {
    // V segment: per-wave 64(n) x 64(m) transpose patch through LDS.
    char* T = lds + w * 8192;
#pragma unroll
    for (int i = 0; i < 4; ++i)
#pragma unroll
      for (int j = 0; j < 4; ++j) {
        int nn = j * 16 + l15;
        int md0 = i * 8 + quad * 2;
        uint32 p01 = (uint32)f2bf(acc[i][j][0]) | ((uint32)f2bf(acc[i][j][1]) << 16);
        uint32 p23 = (uint32)f2bf(acc[i][j][2]) | ((uint32)f2bf(acc[i][j][3]) << 16);
        *(uint32*)(T + nn * 128 + ((md0 ^ (nn & 31)) * 4)) = p01;
        *(uint32*)(T + nn * 128 + (((md0 + 1) ^ (nn & 31)) * 4)) = p23;
      }
    const int b = (int)(bm0 >> 11);
    const int s0 = (int)(bm0 & 2047) + wr;
    const int n2 = (int)(bn0 & 2047) + wc;
#pragma unroll
    for (int it = 0; it < 32; ++it) {
      int row = it * 2 + (lane >> 5);
      int pp = lane & 31;
      uint32 dv = *(const uint32*)(T + row * 128 + pp * 4);
      int md = pp ^ (row & 31);
      int nloc = n2 + row;
      size_t bh = (size_t)b * 16 + (nloc >> 7);
      *(uint32*)(Vt + (bh * 128 + (size_t)(nloc & 127)) * 2048 + s0 + 2 * md) = dv;
    }
  }
}

// ---------------------------------------------------------------------------
// Output projection: out[4096,2048] fp32 = Ob x WtO^T. Grid 256 = 1 round.
__global__ __launch_bounds__(512, 2) void gemm_wo_kernel(
    const ushort_t* __restrict__ A, const ushort_t* __restrict__ Bt,
    float* __restrict__ out) {
  __shared__ char lds[98304];
  const int tid = (int)threadIdx.x;
  const int w = tid >> 6, lane = tid & 63, quad = lane >> 4, l15 = lane & 15;
  const int wr = (w >> 2) * 64, wc = (w & 3) * 64;

  const int wg = ((int)blockIdx.x & 7) * 32 + ((int)blockIdx.x >> 3);
  const size_t bm0 = (size_t)(wg & 31) * 128;
  const size_t bn0 = (size_t)(wg >> 5) * 256;

  f32x4 acc[4][4];
  f32x4 z4 = {0.f, 0.f, 0.f, 0.f};
#pragma unroll
  for (int i = 0; i < 4; ++i)
#pragma unroll
    for (int j = 0; j < 4; ++j) acc[i][j] = z4;

  kloop_128x256(lds, A, Bt, bm0, bn0, acc);

#pragma unroll
  for (int i = 0; i < 4; ++i)
#pragma unroll
    for (int r = 0; r < 4; ++r) {
      size_t m = bm0 + wr + i * 16 + quad * 4 + r;
#pragma unroll
      for (int j = 0; j < 4; ++j) {
        size_t n = bn0 + wc + j * 16 + l15;
        out[m * 2048 + n] = acc[i][j][r];
      }
    }
}

// ---------------------------------------------------------------------------
// Flash attention, causal, + fused adapter attention.
// R14: setprio around QK/PV MFMA clusters; adapter epilogue reads ak/av
// (fp32) directly with inline l>=10 masking (adapter_pack removed).
// 128q/block, K/V dbuf (vmcnt(8)), defer-max THR=8, dpp+cvt_pk P-store.
__global__ __launch_bounds__(256) void flash_kernel(
    const ushort_t* __restrict__ Qb, const ushort_t* __restrict__ Kb,
    const ushort_t* __restrict__ Vt, const float* __restrict__ ak,
    const float* __restrict__ av, const float* __restrict__ gate,
    ushort_t* __restrict__ Ob) {
  __shared__ char ldsK[32768];   // 2 x (64 tok x 256B), chunk swz ^(row&15)
  __shared__ char ldsV[32768];   // 2 x (128 d x 128B), chunk swz ^(dr&7)
  __shared__ char ldsP[16384];   // loop: P 128q x 128B swz; epilogue: pa[128][40]
  const int tid = threadIdx.x;
  const int w = tid >> 6, lane = tid & 63, quad = lane >> 4, l15 = lane & 15;
  const int idx = blockIdx.x;
  const int p = idx >> 8, c = idx & 255;
  const int u = c >> 4, vv = c & 15;
  const int qt = p ? (15 - u) : u;
  const int hb = (p << 4) | vv;
  const int h = hb >> 1, b = hb & 1;
  const float scale = 0.08838834764831845f;  // 1/sqrt(128)

  bf16x8 ones;
#pragma unroll
  for (int j = 0; j < 8; ++j) ones[j] = (short)0x3F80;

  // Q fragments in registers: 2 m-tiles x 4 d-steps (wave rows w*32..+31)
  bf16x8 qf[2][4];
#pragma unroll
  for (int mt = 0; mt < 2; ++mt) {
    size_t qrow = (size_t)qt * 128 + w * 32 + mt * 16 + l15;
    const ushort_t* base = Qb + ((size_t)b * 2048 + qrow) * 2048 + h * 128 + quad * 8;
#pragma unroll
    for (int ds = 0; ds < 4; ++ds) qf[mt][ds] = *(const bf16x8*)(base + ds * 32);
  }

  f32x4 zero4 = {0.f, 0.f, 0.f, 0.f};
  f32x4 oacc[2][8];
  f32x4 osum[2];
  float mrow[2][4];
#pragma unroll
  for (int mt = 0; mt < 2; ++mt) {
#pragma unroll
    for (int n8 = 0; n8 < 8; ++n8) oacc[mt][n8] = zero4;
    osum[mt] = zero4;
#pragma unroll
    for (int r = 0; r < 4; ++r) mrow[mt][r] = -1e30f;
  }

// stage K/V tile KT into buffer BUF (8 async16/thread)
#define STAGE_KV(KT, BUF)                                                      \
  do {                                                                         \
    char* bK_ = ldsK + (BUF) * 16384;                                          \
    char* bV_ = ldsV + (BUF) * 16384;                                          \
    _Pragma("unroll") for (int ii = 0; ii < 4; ++ii) {                         \
      int r0 = w * 16 + ii * 4;                                                \
      int row = r0 + (lane >> 4);                                              \
      int cl = (lane & 15) ^ (row & 15);                                       \
      async16(bK_ + r0 * 256,                                                  \
              Kb + ((size_t)b * 2048 + (KT) * 64 + row) * 2048 + h * 128 + cl * 8); \
    }                                                                          \
    _Pragma("unroll") for (int ii = 0; ii < 4; ++ii) {                         \
      int d0 = w * 32 + ii * 8;                                                \
      int dr = d0 + (lane >> 3);                                               \
      int cl = (lane & 7) ^ (dr & 7);                                          \
      async16(bV_ + d0 * 128,                                                  \
              Vt + ((size_t)(b * 16 + h) * 128 + dr) * 2048 + (KT) * 64 + cl * 8); \
    }                                                                          \
  } while (0)

  const int ktmax = 2 * qt + 1;
  STAGE_KV(0, 0);
  for (int kt = 0; kt <= ktmax; ++kt) {
    const int cb = kt & 1;
    if (kt < ktmax) {
      STAGE_KV(kt + 1, cb ^ 1);
      asm volatile("s_waitcnt vmcnt(8)" ::: "memory");   // kt's 8 loads done
    } else {
      asm volatile("s_waitcnt vmcnt(0)" ::: "memory");
    }
    QK_BARX();
    const char* bK = ldsK + cb * 16384;
    const char* bV = ldsV + cb * 16384;

    // S = Q K^T
    f32x4 sacc[2][4];
#pragma unroll
    for (int mt = 0; mt < 2; ++mt)
#pragma unroll
      for (int nt = 0; nt < 4; ++nt) sacc[mt][nt] = zero4;
#pragma unroll
    for (int ds = 0; ds < 4; ++ds) {
      bf16x8 kf[4];
      int ch = ds * 4 + quad;
#pragma unroll
      for (int nt = 0; nt < 4; ++nt) {
        int row = nt * 16 + l15;
        kf[nt] = *(const bf16x8*)(bK + row * 256 + ((ch ^ (row & 15)) * 16));
      }
      __builtin_amdgcn_s_setprio(1);
#pragma unroll
      for (int mt = 0; mt < 2; ++mt)
#pragma unroll
        for (int nt = 0; nt < 4; ++nt)
          sacc[mt][nt] = __builtin_amdgcn_mfma_f32_16x16x32_bf16(qf[mt][ds], kf[nt], sacc[mt][nt], 0, 0, 0);
      __builtin_amdgcn_s_setprio(0);
    }

    // online softmax (defer-max, THR=8)
    const bool domask = (kt >= 2 * qt);
    float tmax2[2][4];
    float need = 0.f;
#pragma unroll
    for (int mt = 0; mt < 2; ++mt) {
      float tmax[4] = {-1e30f, -1e30f, -1e30f, -1e30f};
      const int qbase = qt * 128 + w * 32 + mt * 16 + quad * 4;
#pragma unroll
      for (int nt = 0; nt < 4; ++nt) {
        int kg = kt * 64 + nt * 16 + l15;
#pragma unroll
        for (int r = 0; r < 4; ++r) {
          float s = sacc[mt][nt][r] * scale;
          if (domask && kg > qbase + r) s = -1e30f;
          sacc[mt][nt][r] = s;
          tmax[r] = fmaxf(tmax[r], s);
        }
      }
#pragma unroll
      for (int r = 0; r < 4; ++r) {
        tmax2[mt][r] = rowmax16(tmax[r]);
        need = fmaxf(need, tmax2[mt][r] - mrow[mt][r]);
      }
    }
    if (__any(need > 8.0f)) {
#pragma unroll
      for (int mt = 0; mt < 2; ++mt) {
        float alpha[4];
#pragma unroll
        for (int r = 0; r < 4; ++r) {
          float mnew = fmaxf(mrow[mt][r], tmax2[mt][r]);
          alpha[r] = __expf(mrow[mt][r] - mnew);
          osum[mt][r] *= alpha[r];
          mrow[mt][r] = mnew;
        }
#pragma unroll
        for (int n8 = 0; n8 < 8; ++n8)
#pragma unroll
          for (int r = 0; r < 4; ++r) oacc[mt][n8][r] *= alpha[r];
      }
    }
    // P = exp(s - mrow); pack col pairs (l, l^1) via dpp + cvt_pk, even lanes
    // store dwords into swizzled ldsP.
#pragma unroll
    for (int mt = 0; mt < 2; ++mt) {
      uint32 pk[4][4];
#pragma unroll
      for (int nt = 0; nt < 4; ++nt)
#pragma unroll
        for (int r = 0; r < 4; ++r) {
          float pv = __expf(sacc[mt][nt][r] - mrow[mt][r]);
          float pn = dpp_xor1(pv);
          uint32 d_;
          asm volatile("v_cvt_pk_bf16_f32 %0, %1, %2" : "=v"(d_) : "v"(pv), "v"(pn));
          pk[nt][r] = d_;
        }
      if (!(lane & 1)) {
#pragma unroll
        for (int nt = 0; nt < 4; ++nt)
#pragma unroll
          for (int r = 0; r < 4; ++r) {
            int col = nt * 16 + l15;   // even
            int prow = w * 32 + mt * 16 + quad * 4 + r;
            *(uint32*)(ldsP + prow * 128 + (((col >> 3) ^ (prow & 7)) * 16) + (col & 7) * 2) = pk[nt][r];
          }
      }
    }

    // O += P V ; osum += P 1
#pragma unroll
    for (int ks = 0; ks < 2; ++ks) {
      int ch = ks * 4 + quad;
      bf16x8 pf[2];
#pragma unroll
      for (int mt = 0; mt < 2; ++mt) {
        int prow = w * 32 + mt * 16 + l15;
        pf[mt] = *(const bf16x8*)(ldsP + prow * 128 + ((ch ^ (prow & 7)) * 16));
      }
      __builtin_amdgcn_s_setprio(1);
#pragma unroll
      for (int mt = 0; mt < 2; ++mt)
        osum[mt] = __builtin_amdgcn_mfma_f32_16x16x32_bf16(pf[mt], ones, osum[mt], 0, 0, 0);
#pragma unroll
      for (int n8 = 0; n8 < 8; ++n8) {
        int dr = n8 * 16 + l15;
        bf16x8 vf = *(const bf16x8*)(bV + dr * 128 + ((ch ^ (dr & 7)) * 16));
#pragma unroll
        for (int mt = 0; mt < 2; ++mt)
          oacc[mt][n8] = __builtin_amdgcn_mfma_f32_16x16x32_bf16(pf[mt], vf, oacc[mt][n8], 0, 0, 0);
      }
      __builtin_amdgcn_s_setprio(0);
    }
    QK_BARX();
  }
#undef STAGE_KV

  // ---------------- fused adapter epilogue (direct ak/av reads) ----------
  const float g = gate[h];
  {
    int row = w * 32 + (lane >> 1);
    int koff = 16 + (lane & 1) * 8;
    *(uint4*)(ldsP + row * 80 + koff * 2) = make_uint4(0, 0, 0, 0);
  }
  f32x4 sa[2] = {zero4, zero4};
#pragma unroll
  for (int ds = 0; ds < 4; ++ds) {
    bf16x8 kfa;
    if (l15 < 10) {
      const float* akp = ak + (size_t)l15 * 2048 + h * 128 + ds * 32 + quad * 8;
      float4 a = *(const float4*)akp;
      float4 bb = *(const float4*)(akp + 4);
      kfa[0] = (short)f2bf(a.x);  kfa[1] = (short)f2bf(a.y);
      kfa[2] = (short)f2bf(a.z);  kfa[3] = (short)f2bf(a.w);
      kfa[4] = (short)f2bf(bb.x); kfa[5] = (short)f2bf(bb.y);
      kfa[6] = (short)f2bf(bb.z); kfa[7] = (short)f2bf(bb.w);
    } else {
#pragma unroll
      for (int j = 0; j < 8; ++j) kfa[j] = (short)0;
    }
#pragma unroll
    for (int mt = 0; mt < 2; ++mt)
      sa[mt] = __builtin_amdgcn_mfma_f32_16x16x32_bf16(qf[mt][ds], kfa, sa[mt], 0, 0, 0);
  }
#pragma unroll
  for (int mt = 0; mt < 2; ++mt) {
#pragma unroll
    for (int r = 0; r < 4; ++r) {
      float s = sa[mt][r] * scale;
      if (l15 >= 10) s = -1e30f;
      float mx = rowmax16(s);
      float e = __expf(s - mx);
      float sum = rowsum16(e);
      float pv = g * e / sum;
      int row = w * 32 + mt * 16 + quad * 4 + r;
      *(ushort_t*)(ldsP + row * 80 + l15 * 2) = f2bf(pv);
    }
  }
  bf16x8 paf[2];
#pragma unroll
  for (int mt = 0; mt < 2; ++mt)
    paf[mt] = *(const bf16x8*)(ldsP + (w * 32 + mt * 16 + l15) * 80 + quad * 16);

  // normalize main attention
#pragma unroll
  for (int mt = 0; mt < 2; ++mt) {
    float rl[4];
#pragma unroll
    for (int r = 0; r < 4; ++r) rl[r] = 1.f / osum[mt][r];
#pragma unroll
    for (int n8 = 0; n8 < 8; ++n8)
#pragma unroll
      for (int r = 0; r < 4; ++r) oacc[mt][n8][r] *= rl[r];
  }
  // += pa @ av (av read directly; lane supplies l = quad*8+j, zero for l>=10)
#pragma unroll
  for (int n8 = 0; n8 < 8; ++n8) {
    bf16x8 avf;
    int d = n8 * 16 + l15;
    const float* avp = av + (size_t)(quad * 8) * 2048 + h * 128 + d;
#pragma unroll
    for (int j = 0; j < 8; ++j) {
      int l = quad * 8 + j;
      avf[j] = (l < 10) ? (short)f2bf(avp[(size_t)j * 2048]) : (short)0;
    }
#pragma unroll
    for (int mt = 0; mt < 2; ++mt)
      oacc[mt][n8] = __builtin_amdgcn_mfma_f32_16x16x32_bf16(paf[mt], avf, oacc[mt][n8], 0, 0, 0);
  }
#pragma unroll
  for (int mt = 0; mt < 2; ++mt) {
    size_t qb0 = (size_t)qt * 128 + w * 32 + mt * 16 + quad * 4;
#pragma unroll
    for (int n8 = 0; n8 < 8; ++n8) {
      size_t col = (size_t)h * 128 + n8 * 16 + l15;
#pragma unroll
      for (int r = 0; r < 4; ++r)
        Ob[((size_t)b * 2048 + qb0 + r) * 2048 + col] = f2bf(oacc[mt][n8][r]);
    }
  }
}

// ---------------------------------------------------------------------------
extern "C" void kernel_launch(void* const* d_in, const int* in_sizes, int n_in,
                              void* d_out, int out_size, void* d_ws, size_t ws_size,
                              hipStream_t stream) {
  (void)in_sizes; (void)n_in; (void)out_size; (void)ws_size;
  const float* x       = (const float*)d_in[0];
  const float* wq      = (const float*)d_in[1];
  const float* wk      = (const float*)d_in[2];
  const float* wv      = (const float*)d_in[3];
  const float* wo      = (const float*)d_in[4];
  const float* adapter = (const float*)d_in[5];
  const float* gate    = (const float*)d_in[6];
  const float* fc      = (const float*)d_in[7];
  const float* fs      = (const float*)d_in[8];

  char* ws = (char*)d_ws;
  ushort_t* Xb   = (ushort_t*)(ws + 0);           // 16 MB (reused as Ob)
  ushort_t* WtQ  = (ushort_t*)(ws + 16777216);    // 8 MB x4 contiguous
  ushort_t* WtO  = (ushort_t*)(ws + 41943040);
  ushort_t* Qb   = (ushort_t*)(ws + 50331648);    // 16 MB
  ushort_t* Kb   = (ushort_t*)(ws + 67108864);    // 16 MB
  ushort_t* Vt   = (ushort_t*)(ws + 83886080);    // 16 MB
  float*    ak   = (float*)   (ws + 100663296);   // 80 KB
  float*    av   = (float*)   (ws + 100745216);   // 80 KB
  ushort_t* Ob   = Xb;

  hipMemsetAsync(ak, 0, 163840, stream);
  prep_kernel<<<8448, 256, 0, stream>>>(x, Xb, wq, wk, wv, wo, WtQ,
                                        adapter, ak, av);
  gemm_qkv128_kernel<<<dim3(768), 512, 0, stream>>>(Xb, WtQ, Qb, Kb, Vt, fc, fs);
  flash_kernel<<<dim3(512), 256, 0, stream>>>(Qb, Kb, Vt, ak, av, gate, Ob);
  gemm_wo_kernel<<<dim3(256), 512, 0, stream>>>(Ob, WtO, (float*)d_out);
}

// Round 10
// 429.690 us; speedup vs baseline: 1.0503x; 1.0503x over previous
//
#include <hip/hip_runtime.h>

// ---------------------------------------------------------------------------
// Attention_16698832847178: B=2,S=2048,D=2048,H=16,HD=128,L=10
// R15 = R13 (best verified, 421.3us): R14's setprio-in-lockstep-block and
// direct-ak/av-epilogue both regressed (451.3); reverted. Components:
// - qkv/wo: 128x256 pipelined kloop, vmcnt(3), 873 TF (m97-ceiling).
// - flash: 128q/block mt=2, K/V dbuf vmcnt(8), defer-max THR=8,
//   dpp+v_cvt_pk_bf16_f32 packed P-store, fused adapter epilogue via akb/avb.
// - prep: cast_x + transpose_w + adapter_kv merged (1 dispatch).
// ---------------------------------------------------------------------------

typedef unsigned short ushort_t;
typedef unsigned int uint32;
typedef __attribute__((ext_vector_type(8))) short bf16x8;   // 8 bf16 = 4 VGPRs
typedef __attribute__((ext_vector_type(4))) float f32x4;

__device__ __forceinline__ void async16(void* lds, const void* g) {
  __builtin_amdgcn_global_load_lds((const __attribute__((address_space(1))) void*)g,
                                   (__attribute__((address_space(3))) void*)lds,
                                   16, 0, 0);
}
__device__ __forceinline__ ushort_t f2bf(float f) {
  uint32 u = __float_as_uint(f);
  u += 0x7FFFu + ((u >> 16) & 1u);   // round-to-nearest-even
  return (ushort_t)(u >> 16);
}
__device__ __forceinline__ float bf2f(ushort_t b) {
  return __uint_as_float(((uint32)b) << 16);
}
// value from lane^1 via DPP quad_perm [1,0,3,2] (VALU, no LDS)
__device__ __forceinline__ float dpp_xor1(float v) {
  return __int_as_float(__builtin_amdgcn_update_dpp(
      0, __float_as_int(v), 0xB1, 0xf, 0xf, true));
}
#define DPP_MAX(t, ctrl) \
  t = fmaxf(t, __int_as_float(__builtin_amdgcn_update_dpp( \
      0, __float_as_int(t), (ctrl), 0xf, 0xf, true)))
#define DPP_ADD(t, ctrl) \
  t += __int_as_float(__builtin_amdgcn_update_dpp( \
      0, __float_as_int(t), (ctrl), 0xf, 0xf, true))
__device__ __forceinline__ float rowmax16(float t) {
  DPP_MAX(t, 0xB1);   // xor 1
  DPP_MAX(t, 0x4E);   // xor 2
  t = fmaxf(t, __int_as_float(__builtin_amdgcn_ds_swizzle(
      __float_as_int(t), 0x101F)));                  // xor 4
  DPP_MAX(t, 0x128);  // row_ror:8 -> xor 8 (halves uniform after xor1/2/4)
  return t;
}
__device__ __forceinline__ float rowsum16(float t) {
  DPP_ADD(t, 0xB1);
  DPP_ADD(t, 0x4E);
  t += __int_as_float(__builtin_amdgcn_ds_swizzle(__float_as_int(t), 0x101F));
  DPP_ADD(t, 0x128);
  return t;
}

// ---------------------------------------------------------------------------
// Merged preprocessing: [0,4096) cast x->bf16; [4096,8192) transpose W;
// [8192,8448) adapter projections (atomic, 256-block layout as before).
__global__ __launch_bounds__(256) void prep_kernel(
    const float* __restrict__ x, ushort_t* __restrict__ Xb,
    const float* __restrict__ w0, const float* __restrict__ w1,
    const float* __restrict__ w2, const float* __restrict__ w3,
    ushort_t* __restrict__ WtBase,
    const float* __restrict__ adapter,
    float* __restrict__ ak, float* __restrict__ av) {
  __shared__ float L[64][65];
  const int bid = (int)blockIdx.x;
  const int t = (int)threadIdx.x;

  if (bid < 4096) {
    // ---- cast x (fp32) -> bf16, 8 elements/thread ----
    size_t i = ((size_t)bid * 256 + t) * 8;
    float4 a = *(const float4*)(x + i);
    float4 b = *(const float4*)(x + i + 4);
    uint4 o;
    o.x = (uint32)f2bf(a.x) | ((uint32)f2bf(a.y) << 16);
    o.y = (uint32)f2bf(a.z) | ((uint32)f2bf(a.w) << 16);
    o.z = (uint32)f2bf(b.x) | ((uint32)f2bf(b.y) << 16);
    o.w = (uint32)f2bf(b.z) | ((uint32)f2bf(b.w) << 16);
    *(uint4*)(Xb + i) = o;
    return;
  }
  if (bid < 8192) {
    // ---- W[k][n] fp32 -> Wt[n][k] bf16 (64x64 tiles) ----
    int c = bid - 4096;
    const int z = c >> 10, rem = c & 1023;
    const int bx = rem & 31, by = rem >> 5;
    const float* W = (z == 0) ? w0 : (z == 1) ? w1 : (z == 2) ? w2 : w3;
    ushort_t* Wt = WtBase + (size_t)z * 4194304;  // 2048*2048
    int tc = t & 63, tr = t >> 6;
    int k0 = bx * 64, n0 = by * 64;
    for (int i = 0; i < 16; ++i) {
      int r = i * 4 + tr;
      L[r][tc] = W[(size_t)(k0 + r) * 2048 + n0 + tc];
    }
    __syncthreads();
    int tr8 = t >> 5, tc2 = t & 31;
    for (int i = 0; i < 8; ++i) {
      int r = i * 8 + tr8;
      uint32 pk = (uint32)f2bf(L[2 * tc2][r]) | ((uint32)f2bf(L[2 * tc2 + 1][r]) << 16);
      *(uint32*)(Wt + (size_t)(n0 + r) * 2048 + k0 + 2 * tc2) = pk;
    }
    return;
  }
  {
    // ---- adapter: ak/av[l][n] = sum_k adapter[l][k] * W[k][n] ----
    int c = bid - 8192;               // [0,256)
    const int z = c >> 7;             // 0=wk, 1=wv
    const int ky = (c >> 3) & 15;     // k-chunk
    const int xx = c & 7;             // n-chunk
    const float* W = z ? w2 : w1;     // wv : wk
    float* out = z ? av : ak;
    float (*As)[128] = (float(*)[128])L;
    int k0 = ky * 128;
    for (int i = t; i < 1280; i += 256)
      As[i >> 7][i & 127] = adapter[(size_t)(i >> 7) * 2048 + k0 + (i & 127)];
    __syncthreads();
    int n = xx * 256 + t;
    float acc[10];
#pragma unroll
    for (int l = 0; l < 10; ++l) acc[l] = 0.f;
    for (int kk = 0; kk < 128; ++kk) {
      float wv_ = W[(size_t)(k0 + kk) * 2048 + n];
#pragma unroll
      for (int l = 0; l < 10; ++l) acc[l] += As[l][kk] * wv_;
    }
#pragma unroll
    for (int l = 0; l < 10; ++l) atomicAdd(&out[l * 2048 + n], acc[l]);
  }
}

// ---------------------------------------------------------------------------
// pack ak/av (fp32) into MFMA-fragment-friendly bf16 buffers:
// akb[h][l(16)][d(128)] (l>=10 zero), avb[h][d(128)][l(32)] (l>=10 zero)
__global__ __launch_bounds__(256) void adapter_pack_kernel(
    const float* __restrict__ ak, const float* __restrict__ av,
    ushort_t* __restrict__ akb, ushort_t* __restrict__ avb) {
  int t = blockIdx.x * 256 + threadIdx.x;   // 65536 threads
  if (t < 32768) {
    int h = t >> 11, l = (t >> 7) & 15, d = t & 127;
    akb[t] = (l < 10) ? f2bf(ak[l * 2048 + h * 128 + d]) : (ushort_t)0;
  }
  int h = t >> 12, d = (t >> 5) & 127, l = t & 31;
  avb[t] = (l < 10) ? f2bf(av[l * 2048 + h * 128 + d]) : (ushort_t)0;
}

#define QK_BARX() asm volatile("s_barrier" ::: "memory")
#define QK_LGKM0() asm volatile("s_waitcnt lgkmcnt(0)" ::: "memory")

// ---------------------------------------------------------------------------
// R8's proven pipelined 128x256 K-loop (A and B in LDS).
__device__ __forceinline__ void kloop_128x256(
    char* lds, const ushort_t* __restrict__ A, const ushort_t* __restrict__ Bt,
    size_t bm0, size_t bn0, f32x4 (&acc)[4][4]) {
  const int tid = (int)threadIdx.x;
  const int w = tid >> 6, lane = tid & 63, quad = lane >> 4, l15 = lane & 15;
  const int wr = (w >> 2) * 64, wc = (w & 3) * 64;
  const int nt = 32;
  char* const pA0 = lds;
  char* const pA1 = lds + 16384;
  char* const pB0 = lds + 32768;
  char* const pB1 = lds + 65536;

#define PAT(T) (((T) & 1) ? pA1 : pA0)
#define PBT(T) (((T) & 1) ? pB1 : pB0)
#define SEGL(OP, LDSB, GROW, T)                                                \
  do {                                                                         \
    int rr_ = w * 8 + (lane >> 3);                                             \
    int cl_ = (lane & 7) ^ (rr_ & 7);                                          \
    async16((LDSB) + w * 1024,                                                 \
            (OP) + ((GROW) + (size_t)rr_) * 2048 + (size_t)((T) * 64 + cl_ * 8)); \
  } while (0)
#define ST_A(T)                                                                \
  do { if ((T) < nt) { SEGL(A, PAT(T), bm0, (T));                              \
                       SEGL(A, PAT(T) + 8192, bm0 + 64, (T)); } } while (0)
#define ST_B0(T)                                                               \
  do { if ((T) < nt) SEGL(Bt, PBT(T), bn0, (T)); } while (0)
#define ST_B123(T)                                                             \
  do { if ((T) < nt) { SEGL(Bt, PBT(T) + 8192,  bn0 + 64,  (T));               \
                       SEGL(Bt, PBT(T) + 16384, bn0 + 128, (T));               \
                       SEGL(Bt, PBT(T) + 24576, bn0 + 192, (T)); } } while (0)

  ST_A(0); ST_B0(0); ST_B123(0); ST_B123(1);
  asm volatile("s_waitcnt vmcnt(3)" ::: "memory");
  QK_BARX();

#pragma unroll 2
  for (int t = 0; t < nt; ++t) {
    const char* pA = PAT(t);
    const char* pB = PBT(t);
    bf16x8 bfv[4][2];
#pragma unroll
    for (int j = 0; j < 4; ++j) {
      int brow = wc + j * 16 + l15;
#pragma unroll
      for (int ks = 0; ks < 2; ++ks)
        bfv[j][ks] = *(const bf16x8*)(pB + brow * 128 +
                                      (((ks * 4 + quad) ^ (brow & 7)) * 16));
    }
#pragma unroll
    for (int ph = 0; ph < 2; ++ph) {
      bf16x8 af[2][2];
#pragma unroll
      for (int ii = 0; ii < 2; ++ii) {
        int arow = wr + (ph * 2 + ii) * 16 + l15;
#pragma unroll
        for (int ks = 0; ks < 2; ++ks)
          af[ii][ks] = *(const bf16x8*)(pA + arow * 128 +
                                        (((ks * 4 + quad) ^ (arow & 7)) * 16));
      }
      if (ph == 0) { ST_A(t + 1); ST_B0(t + 1); }
      else         { ST_B123(t + 2); }
      QK_BARX();
      QK_LGKM0();
      __builtin_amdgcn_s_setprio(1);
#pragma unroll
      for (int ks = 0; ks < 2; ++ks)
#pragma unroll
        for (int ii = 0; ii < 2; ++ii)
#pragma unroll
          for (int j = 0; j < 4; ++j)
            acc[ph * 2 + ii][j] = __builtin_amdgcn_mfma_f32_16x16x32_bf16(
                af[ii][ks], bfv[j][ks], acc[ph * 2 + ii][j], 0, 0, 0);
      __builtin_amdgcn_s_setprio(0);
      if (ph == 1) {
        if (t == nt - 2) asm volatile("s_waitcnt vmcnt(0)" ::: "memory");
        else             asm volatile("s_waitcnt vmcnt(3)" ::: "memory");
      }
      QK_BARX();
    }
  }
#undef PAT
#undef PBT
#undef SEGL
#undef ST_A
#undef ST_B0
#undef ST_B123
}

// ---------------------------------------------------------------------------
// Fused QKV GEMM: C[4096,6144] = Xb[4096,2048] x WtQKV[6144,2048]^T.
// Grid 768 (32 M x 24 N) = exactly 3 rounds of 256 CUs.
__global__ __launch_bounds__(512, 2) void gemm_qkv128_kernel(
    const ushort_t* __restrict__ A, const ushort_t* __restrict__ Bt,
    ushort_t* __restrict__ outQ, ushort_t* __restrict__ outK,
    ushort_t* __restrict__ Vt,
    const float* __restrict__ fc, const float* __restrict__ fs) {
  __shared__ char lds[98304];
  const int tid = (int)threadIdx.x;
  const int w = tid >> 6, lane = tid & 63, quad = lane >> 4, l15 = lane & 15;
  const int wr = (w >> 2) * 64, wc = (w & 3) * 64;

  const int wg = ((int)blockIdx.x & 7) * 96 + ((int)blockIdx.x >> 3);
  const size_t bm0 = (size_t)(wg & 31) * 128;
  const size_t bn0 = (size_t)(wg >> 5) * 256;

  f32x4 acc[4][4];
  f32x4 z4 = {0.f, 0.f, 0.f, 0.f};
#pragma unroll
  for (int i = 0; i < 4; ++i)
#pragma unroll
    for (int j = 0; j < 4; ++j) acc[i][j] = z4;

  kloop_128x256(lds, A, Bt, bm0, bn0, acc);

  const int seg = (int)(bn0 >> 11);   // 0=Q, 1=K, 2=V
  if (seg < 2) {
    ushort_t* ob = seg ? outK : outQ;
#pragma unroll
    for (int i = 0; i < 4; ++i)
#pragma unroll
      for (int r = 0; r < 4; ++r) {
        size_t m = bm0 + wr + i * 16 + quad * 4 + r;
        int s = (int)(m & 2047);
#pragma unroll
        for (int j = 0; j < 4; ++j) {
          size_t n = (bn0 + wc + j * 16 + l15) & 2047;
          float v = acc[i][j][r];
          float v2 = dpp_xor1(v);             // RoPE pair partner (col n^1)
          int fi = ((int)n & 127) >> 1;
          float cosv = fc[s * 64 + fi];
          float sinv = fs[s * 64 + fi];
          v = (lane & 1) ? (v2 * sinv + v * cosv) : (v * cosv - v2 * sinv);
          ob[m * 2048 + n] = f2bf(v);
        }
      }
  } else {
    // V segment: per-wave 64(n) x 64(m) transpose patch through LDS.
    char* T = lds + w * 8192;
#pragma unroll
    for (int i = 0; i < 4; ++i)
#pragma unroll
      for (int j = 0; j < 4; ++j) {
        int nn = j * 16 + l15;
        int md0 = i * 8 + quad * 2;
        uint32 p01 = (uint32)f2bf(acc[i][j][0]) | ((uint32)f2bf(acc[i][j][1]) << 16);
        uint32 p23 = (uint32)f2bf(acc[i][j][2]) | ((uint32)f2bf(acc[i][j][3]) << 16);
        *(uint32*)(T + nn * 128 + ((md0 ^ (nn & 31)) * 4)) = p01;
        *(uint32*)(T + nn * 128 + (((md0 + 1) ^ (nn & 31)) * 4)) = p23;
      }
    const int b = (int)(bm0 >> 11);
    const int s0 = (int)(bm0 & 2047) + wr;
    const int n2 = (int)(bn0 & 2047) + wc;
#pragma unroll
    for (int it = 0; it < 32; ++it) {
      int row = it * 2 + (lane >> 5);
      int pp = lane & 31;
      uint32 dv = *(const uint32*)(T + row * 128 + pp * 4);
      int md = pp ^ (row & 31);
      int nloc = n2 + row;
      size_t bh = (size_t)b * 16 + (nloc >> 7);
      *(uint32*)(Vt + (bh * 128 + (size_t)(nloc & 127)) * 2048 + s0 + 2 * md) = dv;
    }
  }
}

// ---------------------------------------------------------------------------
// Output projection: out[4096,2048] fp32 = Ob x WtO^T. Grid 256 = 1 round.
__global__ __launch_bounds__(512, 2) void gemm_wo_kernel(
    const ushort_t* __restrict__ A, const ushort_t* __restrict__ Bt,
    float* __restrict__ out) {
  __shared__ char lds[98304];
  const int tid = (int)threadIdx.x;
  const int w = tid >> 6, lane = tid & 63, quad = lane >> 4, l15 = lane & 15;
  const int wr = (w >> 2) * 64, wc = (w & 3) * 64;

  const int wg = ((int)blockIdx.x & 7) * 32 + ((int)blockIdx.x >> 3);
  const size_t bm0 = (size_t)(wg & 31) * 128;
  const size_t bn0 = (size_t)(wg >> 5) * 256;

  f32x4 acc[4][4];
  f32x4 z4 = {0.f, 0.f, 0.f, 0.f};
#pragma unroll
  for (int i = 0; i < 4; ++i)
#pragma unroll
    for (int j = 0; j < 4; ++j) acc[i][j] = z4;

  kloop_128x256(lds, A, Bt, bm0, bn0, acc);

#pragma unroll
  for (int i = 0; i < 4; ++i)
#pragma unroll
    for (int r = 0; r < 4; ++r) {
      size_t m = bm0 + wr + i * 16 + quad * 4 + r;
#pragma unroll
      for (int j = 0; j < 4; ++j) {
        size_t n = bn0 + wc + j * 16 + l15;
        out[m * 2048 + n] = acc[i][j][r];
      }
    }
}

// ---------------------------------------------------------------------------
// Flash attention, causal, + fused adapter attention.
// 128q/block (4 waves x 32 rows), K/V double-buffered (vmcnt(8)), defer-max
// THR=8, dpp+cvt_pk packed P-store. LDS 80KB; grid 512 => 2 blocks/CU.
__global__ __launch_bounds__(256) void flash_kernel(
    const ushort_t* __restrict__ Qb, const ushort_t* __restrict__ Kb,
    const ushort_t* __restrict__ Vt, const ushort_t* __restrict__ akb,
    const ushort_t* __restrict__ avb, const float* __restrict__ gate,
    ushort_t* __restrict__ Ob) {
  __shared__ char ldsK[32768];   // 2 x (64 tok x 256B), chunk swz ^(row&15)
  __shared__ char ldsV[32768];   // 2 x (128 d x 128B), chunk swz ^(dr&7)
  __shared__ char ldsP[16384];   // loop: P 128q x 128B swz; epilogue: pa[128][40]
  const int tid = threadIdx.x;
  const int w = tid >> 6, lane = tid & 63, quad = lane >> 4, l15 = lane & 15;
  const int idx = blockIdx.x;
  const int p = idx >> 8, c = idx & 255;
  const int u = c >> 4, vv = c & 15;
  const int qt = p ? (15 - u) : u;
  const int hb = (p << 4) | vv;
  const int h = hb >> 1, b = hb & 1;
  const float scale = 0.08838834764831845f;  // 1/sqrt(128)

  bf16x8 ones;
#pragma unroll
  for (int j = 0; j < 8; ++j) ones[j] = (short)0x3F80;

  // Q fragments in registers: 2 m-tiles x 4 d-steps (wave rows w*32..+31)
  bf16x8 qf[2][4];
#pragma unroll
  for (int mt = 0; mt < 2; ++mt) {
    size_t qrow = (size_t)qt * 128 + w * 32 + mt * 16 + l15;
    const ushort_t* base = Qb + ((size_t)b * 2048 + qrow) * 2048 + h * 128 + quad * 8;
#pragma unroll
    for (int ds = 0; ds < 4; ++ds) qf[mt][ds] = *(const bf16x8*)(base + ds * 32);
  }

  f32x4 zero4 = {0.f, 0.f, 0.f, 0.f};
  f32x4 oacc[2][8];
  f32x4 osum[2];
  float mrow[2][4];
#pragma unroll
  for (int mt = 0; mt < 2; ++mt) {
#pragma unroll
    for (int n8 = 0; n8 < 8; ++n8) oacc[mt][n8] = zero4;
    osum[mt] = zero4;
#pragma unroll
    for (int r = 0; r < 4; ++r) mrow[mt][r] = -1e30f;
  }

// stage K/V tile KT into buffer BUF (8 async16/thread)
#define STAGE_KV(KT, BUF)                                                      \
  do {                                                                         \
    char* bK_ = ldsK + (BUF) * 16384;                                          \
    char* bV_ = ldsV + (BUF) * 16384;                                          \
    _Pragma("unroll") for (int ii = 0; ii < 4; ++ii) {                         \
      int r0 = w * 16 + ii * 4;                                                \
      int row = r0 + (lane >> 4);                                              \
      int cl = (lane & 15) ^ (row & 15);                                       \
      async16(bK_ + r0 * 256,                                                  \
              Kb + ((size_t)b * 2048 + (KT) * 64 + row) * 2048 + h * 128 + cl * 8); \
    }                                                                          \
    _Pragma("unroll") for (int ii = 0; ii < 4; ++ii) {                         \
      int d0 = w * 32 + ii * 8;                                                \
      int dr = d0 + (lane >> 3);                                               \
      int cl = (lane & 7) ^ (dr & 7);                                          \
      async16(bV_ + d0 * 128,                                                  \
              Vt + ((size_t)(b * 16 + h) * 128 + dr) * 2048 + (KT) * 64 + cl * 8); \
    }                                                                          \
  } while (0)

  const int ktmax = 2 * qt + 1;
  STAGE_KV(0, 0);
  for (int kt = 0; kt <= ktmax; ++kt) {
    const int cb = kt & 1;
    if (kt < ktmax) {
      STAGE_KV(kt + 1, cb ^ 1);
      asm volatile("s_waitcnt vmcnt(8)" ::: "memory");   // kt's 8 loads done
    } else {
      asm volatile("s_waitcnt vmcnt(0)" ::: "memory");
    }
    QK_BARX();
    const char* bK = ldsK + cb * 16384;
    const char* bV = ldsV + cb * 16384;

    // S = Q K^T
    f32x4 sacc[2][4];
#pragma unroll
    for (int mt = 0; mt < 2; ++mt)
#pragma unroll
      for (int nt = 0; nt < 4; ++nt) sacc[mt][nt] = zero4;
#pragma unroll
    for (int ds = 0; ds < 4; ++ds) {
      bf16x8 kf[4];
      int ch = ds * 4 + quad;
#pragma unroll
      for (int nt = 0; nt < 4; ++nt) {
        int row = nt * 16 + l15;
        kf[nt] = *(const bf16x8*)(bK + row * 256 + ((ch ^ (row & 15)) * 16));
      }
#pragma unroll
      for (int mt = 0; mt < 2; ++mt)
#pragma unroll
        for (int nt = 0; nt < 4; ++nt)
          sacc[mt][nt] = __builtin_amdgcn_mfma_f32_16x16x32_bf16(qf[mt][ds], kf[nt], sacc[mt][nt], 0, 0, 0);
    }

    // online softmax (defer-max, THR=8)
    const bool domask = (kt >= 2 * qt);
    float tmax2[2][4];
    float need = 0.f;
#pragma unroll
    for (int mt = 0; mt < 2; ++mt) {
      float tmax[4] = {-1e30f, -1e30f, -1e30f, -1e30f};
      const int qbase = qt * 128 + w * 32 + mt * 16 + quad * 4;
#pragma unroll
      for (int nt = 0; nt < 4; ++nt) {
        int kg = kt * 64 + nt * 16 + l15;
#pragma unroll
        for (int r = 0; r < 4; ++r) {
          float s = sacc[mt][nt][r] * scale;
          if (domask && kg > qbase + r) s = -1e30f;
          sacc[mt][nt][r] = s;
          tmax[r] = fmaxf(tmax[r], s);
        }
      }
#pragma unroll
      for (int r = 0; r < 4; ++r) {
        tmax2[mt][r] = rowmax16(tmax[r]);
        need = fmaxf(need, tmax2[mt][r] - mrow[mt][r]);
      }
    }
    if (__any(need > 8.0f)) {
#pragma unroll
      for (int mt = 0; mt < 2; ++mt) {
        float alpha[4];
#pragma unroll
        for (int r = 0; r < 4; ++r) {
          float mnew = fmaxf(mrow[mt][r], tmax2[mt][r]);
          alpha[r] = __expf(mrow[mt][r] - mnew);
          osum[mt][r] *= alpha[r];
          mrow[mt][r] = mnew;
        }
#pragma unroll
        for (int n8 = 0; n8 < 8; ++n8)
#pragma unroll
          for (int r = 0; r < 4; ++r) oacc[mt][n8][r] *= alpha[r];
      }
    }
    // P = exp(s - mrow); pack col pairs (l, l^1) via dpp + cvt_pk, even lanes
    // store dwords into swizzled ldsP.
#pragma unroll
    for (int mt = 0; mt < 2; ++mt) {
      uint32 pk[4][4];
#pragma unroll
      for (int nt = 0; nt < 4; ++nt)
#pragma unroll
        for (int r = 0; r < 4; ++r) {
          float pv = __expf(sacc[mt][nt][r] - mrow[mt][r]);
          float pn = dpp_xor1(pv);
          uint32 d_;
          asm volatile("v_cvt_pk_bf16_f32 %0, %1, %2" : "=v"(d_) : "v"(pv), "v"(pn));
          pk[nt][r] = d_;
        }
      if (!(lane & 1)) {
#pragma unroll
        for (int nt = 0; nt < 4; ++nt)
#pragma unroll
          for (int r = 0; r < 4; ++r) {
            int col = nt * 16 + l15;   // even
            int prow = w * 32 + mt * 16 + quad * 4 + r;
            *(uint32*)(ldsP + prow * 128 + (((col >> 3) ^ (prow & 7)) * 16) + (col & 7) * 2) = pk[nt][r];
          }
      }
    }

    // O += P V ; osum += P 1
#pragma unroll
    for (int ks = 0; ks < 2; ++ks) {
      int ch = ks * 4 + quad;
      bf16x8 pf[2];
#pragma unroll
      for (int mt = 0; mt < 2; ++mt) {
        int prow = w * 32 + mt * 16 + l15;
        pf[mt] = *(const bf16x8*)(ldsP + prow * 128 + ((ch ^ (prow & 7)) * 16));
      }
#pragma unroll
      for (int mt = 0; mt < 2; ++mt)
        osum[mt] = __builtin_amdgcn_mfma_f32_16x16x32_bf16(pf[mt], ones, osum[mt], 0, 0, 0);
#pragma unroll
      for (int n8 = 0; n8 < 8; ++n8) {
        int dr = n8 * 16 + l15;
        bf16x8 vf = *(const bf16x8*)(bV + dr * 128 + ((ch ^ (dr & 7)) * 16));
#pragma unroll
        for (int mt = 0; mt < 2; ++mt)
          oacc[mt][n8] = __builtin_amdgcn_mfma_f32_16x16x32_bf16(pf[mt], vf, oacc[mt][n8], 0, 0, 0);
      }
    }
    QK_BARX();
  }
#undef STAGE_KV

  // ---------------- fused adapter epilogue ----------------
  const float g = gate[h];
  {
    int row = w * 32 + (lane >> 1);
    int koff = 16 + (lane & 1) * 8;
    *(uint4*)(ldsP + row * 80 + koff * 2) = make_uint4(0, 0, 0, 0);
  }
  f32x4 sa[2] = {zero4, zero4};
#pragma unroll
  for (int ds = 0; ds < 4; ++ds) {
    bf16x8 kfa = *(const bf16x8*)(akb + ((size_t)h * 16 + l15) * 128 + ds * 32 + quad * 8);
#pragma unroll
    for (int mt = 0; mt < 2; ++mt)
      sa[mt] = __builtin_amdgcn_mfma_f32_16x16x32_bf16(qf[mt][ds], kfa, sa[mt], 0, 0, 0);
  }
#pragma unroll
  for (int mt = 0; mt < 2; ++mt) {
#pragma unroll
    for (int r = 0; r < 4; ++r) {
      float s = sa[mt][r] * scale;
      if (l15 >= 10) s = -1e30f;
      float mx = rowmax16(s);
      float e = __expf(s - mx);
      float sum = rowsum16(e);
      float pv = g * e / sum;
      int row = w * 32 + mt * 16 + quad * 4 + r;
      *(ushort_t*)(ldsP + row * 80 + l15 * 2) = f2bf(pv);
    }
  }
  bf16x8 paf[2];
#pragma unroll
  for (int mt = 0; mt < 2; ++mt)
    paf[mt] = *(const bf16x8*)(ldsP + (w * 32 + mt * 16 + l15) * 80 + quad * 16);

  // normalize main attention
#pragma unroll
  for (int mt = 0; mt < 2; ++mt) {
    float rl[4];
#pragma unroll
    for (int r = 0; r < 4; ++r) rl[r] = 1.f / osum[mt][r];
#pragma unroll
    for (int n8 = 0; n8 < 8; ++n8)
#pragma unroll
      for (int r = 0; r < 4; ++r) oacc[mt][n8][r] *= rl[r];
  }
  // += pa @ avb ; store bf16
#pragma unroll
  for (int n8 = 0; n8 < 8; ++n8) {
    bf16x8 avf = *(const bf16x8*)(avb + ((size_t)h * 128 + n8 * 16 + l15) * 32 + quad * 8);
#pragma unroll
    for (int mt = 0; mt < 2; ++mt)
      oacc[mt][n8] = __builtin_amdgcn_mfma_f32_16x16x32_bf16(paf[mt], avf, oacc[mt][n8], 0, 0, 0);
  }
#pragma unroll
  for (int mt = 0; mt < 2; ++mt) {
    size_t qb0 = (size_t)qt * 128 + w * 32 + mt * 16 + quad * 4;
#pragma unroll
    for (int n8 = 0; n8 < 8; ++n8) {
      size_t col = (size_t)h * 128 + n8 * 16 + l15;
#pragma unroll
      for (int r = 0; r < 4; ++r)
        Ob[((size_t)b * 2048 + qb0 + r) * 2048 + col] = f2bf(oacc[mt][n8][r]);
    }
  }
}

// ---------------------------------------------------------------------------
extern "C" void kernel_launch(void* const* d_in, const int* in_sizes, int n_in,
                              void* d_out, int out_size, void* d_ws, size_t ws_size,
                              hipStream_t stream) {
  (void)in_sizes; (void)n_in; (void)out_size; (void)ws_size;
  const float* x       = (const float*)d_in[0];
  const float* wq      = (const float*)d_in[1];
  const float* wk      = (const float*)d_in[2];
  const float* wv      = (const float*)d_in[3];
  const float* wo      = (const float*)d_in[4];
  const float* adapter = (const float*)d_in[5];
  const float* gate    = (const float*)d_in[6];
  const float* fc      = (const float*)d_in[7];
  const float* fs      = (const float*)d_in[8];

  char* ws = (char*)d_ws;
  ushort_t* Xb   = (ushort_t*)(ws + 0);           // 16 MB (reused as Ob)
  ushort_t* WtQ  = (ushort_t*)(ws + 16777216);    // 8 MB x4 contiguous
  ushort_t* WtO  = (ushort_t*)(ws + 41943040);
  ushort_t* Qb   = (ushort_t*)(ws + 50331648);    // 16 MB
  ushort_t* Kb   = (ushort_t*)(ws + 67108864);    // 16 MB
  ushort_t* Vt   = (ushort_t*)(ws + 83886080);    // 16 MB
  float*    ak   = (float*)   (ws + 100663296);   // 80 KB
  float*    av   = (float*)   (ws + 100745216);   // 80 KB
  ushort_t* akb  = (ushort_t*)(ws + 100827136);   // 64 KB
  ushort_t* avb  = (ushort_t*)(ws + 100892672);   // 128 KB
  ushort_t* Ob   = Xb;

  hipMemsetAsync(ak, 0, 163840, stream);
  prep_kernel<<<8448, 256, 0, stream>>>(x, Xb, wq, wk, wv, wo, WtQ,
                                        adapter, ak, av);
  adapter_pack_kernel<<<256, 256, 0, stream>>>(ak, av, akb, avb);
  gemm_qkv128_kernel<<<dim3(768), 512, 0, stream>>>(Xb, WtQ, Qb, Kb, Vt, fc, fs);
  flash_kernel<<<dim3(512), 256, 0, stream>>>(Qb, Kb, Vt, akb, avb, gate, Ob);
  gemm_wo_kernel<<<dim3(256), 512, 0, stream>>>(Ob, WtO, (float*)d_out);
}

// Round 11
// 404.686 us; speedup vs baseline: 1.1152x; 1.0618x over previous
//
#include <hip/hip_runtime.h>

// ---------------------------------------------------------------------------
// Attention_16698832847178: B=2,S=2048,D=2048,H=16,HD=128,L=10
// R16: flash k-tile widened 64->128 cols (KVBLK=128): halves the per-tile
// sync/serial costs (barriers 4->2, vmcnt drains 2->1, rowmax chains 16->8,
// rescales <=2-><=1 per 128 cols) at constant LDS traffic. K/V stored as two
// proven 64-wide halves (16KB each); P buffer (16KB) reused across the two
// PV half-passes (wave-private rows -> no barrier needed between halves).
// Prefetch dropped (R13 proved neutral). LDS 80KB, 2 blocks/CU unchanged.
// Everything else identical to R15/R13 (best verified 421.3us).
// ---------------------------------------------------------------------------

typedef unsigned short ushort_t;
typedef unsigned int uint32;
typedef __attribute__((ext_vector_type(8))) short bf16x8;   // 8 bf16 = 4 VGPRs
typedef __attribute__((ext_vector_type(4))) float f32x4;

__device__ __forceinline__ void async16(void* lds, const void* g) {
  __builtin_amdgcn_global_load_lds((const __attribute__((address_space(1))) void*)g,
                                   (__attribute__((address_space(3))) void*)lds,
                                   16, 0, 0);
}
__device__ __forceinline__ ushort_t f2bf(float f) {
  uint32 u = __float_as_uint(f);
  u += 0x7FFFu + ((u >> 16) & 1u);   // round-to-nearest-even
  return (ushort_t)(u >> 16);
}
__device__ __forceinline__ float bf2f(ushort_t b) {
  return __uint_as_float(((uint32)b) << 16);
}
// value from lane^1 via DPP quad_perm [1,0,3,2] (VALU, no LDS)
__device__ __forceinline__ float dpp_xor1(float v) {
  return __int_as_float(__builtin_amdgcn_update_dpp(
      0, __float_as_int(v), 0xB1, 0xf, 0xf, true));
}
#define DPP_MAX(t, ctrl) \
  t = fmaxf(t, __int_as_float(__builtin_amdgcn_update_dpp( \
      0, __float_as_int(t), (ctrl), 0xf, 0xf, true)))
#define DPP_ADD(t, ctrl) \
  t += __int_as_float(__builtin_amdgcn_update_dpp( \
      0, __float_as_int(t), (ctrl), 0xf, 0xf, true))
__device__ __forceinline__ float rowmax16(float t) {
  DPP_MAX(t, 0xB1);   // xor 1
  DPP_MAX(t, 0x4E);   // xor 2
  t = fmaxf(t, __int_as_float(__builtin_amdgcn_ds_swizzle(
      __float_as_int(t), 0x101F)));                  // xor 4
  DPP_MAX(t, 0x128);  // row_ror:8 -> xor 8 (halves uniform after xor1/2/4)
  return t;
}
__device__ __forceinline__ float rowsum16(float t) {
  DPP_ADD(t, 0xB1);
  DPP_ADD(t, 0x4E);
  t += __int_as_float(__builtin_amdgcn_ds_swizzle(__float_as_int(t), 0x101F));
  DPP_ADD(t, 0x128);
  return t;
}

// ---------------------------------------------------------------------------
// Merged preprocessing: [0,4096) cast x->bf16; [4096,8192) transpose W;
// [8192,8448) adapter projections (atomic, 256-block layout as before).
__global__ __launch_bounds__(256) void prep_kernel(
    const float* __restrict__ x, ushort_t* __restrict__ Xb,
    const float* __restrict__ w0, const float* __restrict__ w1,
    const float* __restrict__ w2, const float* __restrict__ w3,
    ushort_t* __restrict__ WtBase,
    const float* __restrict__ adapter,
    float* __restrict__ ak, float* __restrict__ av) {
  __shared__ float L[64][65];
  const int bid = (int)blockIdx.x;
  const int t = (int)threadIdx.x;

  if (bid < 4096) {
    // ---- cast x (fp32) -> bf16, 8 elements/thread ----
    size_t i = ((size_t)bid * 256 + t) * 8;
    float4 a = *(const float4*)(x + i);
    float4 b = *(const float4*)(x + i + 4);
    uint4 o;
    o.x = (uint32)f2bf(a.x) | ((uint32)f2bf(a.y) << 16);
    o.y = (uint32)f2bf(a.z) | ((uint32)f2bf(a.w) << 16);
    o.z = (uint32)f2bf(b.x) | ((uint32)f2bf(b.y) << 16);
    o.w = (uint32)f2bf(b.z) | ((uint32)f2bf(b.w) << 16);
    *(uint4*)(Xb + i) = o;
    return;
  }
  if (bid < 8192) {
    // ---- W[k][n] fp32 -> Wt[n][k] bf16 (64x64 tiles) ----
    int c = bid - 4096;
    const int z = c >> 10, rem = c & 1023;
    const int bx = rem & 31, by = rem >> 5;
    const float* W = (z == 0) ? w0 : (z == 1) ? w1 : (z == 2) ? w2 : w3;
    ushort_t* Wt = WtBase + (size_t)z * 4194304;  // 2048*2048
    int tc = t & 63, tr = t >> 6;
    int k0 = bx * 64, n0 = by * 64;
    for (int i = 0; i < 16; ++i) {
      int r = i * 4 + tr;
      L[r][tc] = W[(size_t)(k0 + r) * 2048 + n0 + tc];
    }
    __syncthreads();
    int tr8 = t >> 5, tc2 = t & 31;
    for (int i = 0; i < 8; ++i) {
      int r = i * 8 + tr8;
      uint32 pk = (uint32)f2bf(L[2 * tc2][r]) | ((uint32)f2bf(L[2 * tc2 + 1][r]) << 16);
      *(uint32*)(Wt + (size_t)(n0 + r) * 2048 + k0 + 2 * tc2) = pk;
    }
    return;
  }
  {
    // ---- adapter: ak/av[l][n] = sum_k adapter[l][k] * W[k][n] ----
    int c = bid - 8192;               // [0,256)
    const int z = c >> 7;             // 0=wk, 1=wv
    const int ky = (c >> 3) & 15;     // k-chunk
    const int xx = c & 7;             // n-chunk
    const float* W = z ? w2 : w1;     // wv : wk
    float* out = z ? av : ak;
    float (*As)[128] = (float(*)[128])L;
    int k0 = ky * 128;
    for (int i = t; i < 1280; i += 256)
      As[i >> 7][i & 127] = adapter[(size_t)(i >> 7) * 2048 + k0 + (i & 127)];
    __syncthreads();
    int n = xx * 256 + t;
    float acc[10];
#pragma unroll
    for (int l = 0; l < 10; ++l) acc[l] = 0.f;
    for (int kk = 0; kk < 128; ++kk) {
      float wv_ = W[(size_t)(k0 + kk) * 2048 + n];
#pragma unroll
      for (int l = 0; l < 10; ++l) acc[l] += As[l][kk] * wv_;
    }
#pragma unroll
    for (int l = 0; l < 10; ++l) atomicAdd(&out[l * 2048 + n], acc[l]);
  }
}

// ---------------------------------------------------------------------------
// pack ak/av (fp32) into MFMA-fragment-friendly bf16 buffers:
// akb[h][l(16)][d(128)] (l>=10 zero), avb[h][d(128)][l(32)] (l>=10 zero)
__global__ __launch_bounds__(256) void adapter_pack_kernel(
    const float* __restrict__ ak, const float* __restrict__ av,
    ushort_t* __restrict__ akb, ushort_t* __restrict__ avb) {
  int t = blockIdx.x * 256 + threadIdx.x;   // 65536 threads
  if (t < 32768) {
    int h = t >> 11, l = (t >> 7) & 15, d = t & 127;
    akb[t] = (l < 10) ? f2bf(ak[l * 2048 + h * 128 + d]) : (ushort_t)0;
  }
  int h = t >> 12, d = (t >> 5) & 127, l = t & 31;
  avb[t] = (l < 10) ? f2bf(av[l * 2048 + h * 128 + d]) : (ushort_t)0;
}

#define QK_BARX() asm volatile("s_barrier" ::: "memory")
#define QK_LGKM0() asm volatile("s_waitcnt lgkmcnt(0)" ::: "memory")

// ---------------------------------------------------------------------------
// R8's proven pipelined 128x256 K-loop (A and B in LDS).
__device__ __forceinline__ void kloop_128x256(
    char* lds, const ushort_t* __restrict__ A, const ushort_t* __restrict__ Bt,
    size_t bm0, size_t bn0, f32x4 (&acc)[4][4]) {
  const int tid = (int)threadIdx.x;
  const int w = tid >> 6, lane = tid & 63, quad = lane >> 4, l15 = lane & 15;
  const int wr = (w >> 2) * 64, wc = (w & 3) * 64;
  const int nt = 32;
  char* const pA0 = lds;
  char* const pA1 = lds + 16384;
  char* const pB0 = lds + 32768;
  char* const pB1 = lds + 65536;

#define PAT(T) (((T) & 1) ? pA1 : pA0)
#define PBT(T) (((T) & 1) ? pB1 : pB0)
#define SEGL(OP, LDSB, GROW, T)                                                \
  do {                                                                         \
    int rr_ = w * 8 + (lane >> 3);                                             \
    int cl_ = (lane & 7) ^ (rr_ & 7);                                          \
    async16((LDSB) + w * 1024,                                                 \
            (OP) + ((GROW) + (size_t)rr_) * 2048 + (size_t)((T) * 64 + cl_ * 8)); \
  } while (0)
#define ST_A(T)                                                                \
  do { if ((T) < nt) { SEGL(A, PAT(T), bm0, (T));                              \
                       SEGL(A, PAT(T) + 8192, bm0 + 64, (T)); } } while (0)
#define ST_B0(T)                                                               \
  do { if ((T) < nt) SEGL(Bt, PBT(T), bn0, (T)); } while (0)
#define ST_B123(T)                                                             \
  do { if ((T) < nt) { SEGL(Bt, PBT(T) + 8192,  bn0 + 64,  (T));               \
                       SEGL(Bt, PBT(T) + 16384, bn0 + 128, (T));               \
                       SEGL(Bt, PBT(T) + 24576, bn0 + 192, (T)); } } while (0)

  ST_A(0); ST_B0(0); ST_B123(0); ST_B123(1);
  asm volatile("s_waitcnt vmcnt(3)" ::: "memory");
  QK_BARX();

#pragma unroll 2
  for (int t = 0; t < nt; ++t) {
    const char* pA = PAT(t);
    const char* pB = PBT(t);
    bf16x8 bfv[4][2];
#pragma unroll
    for (int j = 0; j < 4; ++j) {
      int brow = wc + j * 16 + l15;
#pragma unroll
      for (int ks = 0; ks < 2; ++ks)
        bfv[j][ks] = *(const bf16x8*)(pB + brow * 128 +
                                      (((ks * 4 + quad) ^ (brow & 7)) * 16));
    }
#pragma unroll
    for (int ph = 0; ph < 2; ++ph) {
      bf16x8 af[2][2];
#pragma unroll
      for (int ii = 0; ii < 2; ++ii) {
        int arow = wr + (ph * 2 + ii) * 16 + l15;
#pragma unroll
        for (int ks = 0; ks < 2; ++ks)
          af[ii][ks] = *(const bf16x8*)(pA + arow * 128 +
                                        (((ks * 4 + quad) ^ (arow & 7)) * 16));
      }
      if (ph == 0) { ST_A(t + 1); ST_B0(t + 1); }
      else         { ST_B123(t + 2); }
      QK_BARX();
      QK_LGKM0();
      __builtin_amdgcn_s_setprio(1);
#pragma unroll
      for (int ks = 0; ks < 2; ++ks)
#pragma unroll
        for (int ii = 0; ii < 2; ++ii)
#pragma unroll
          for (int j = 0; j < 4; ++j)
            acc[ph * 2 + ii][j] = __builtin_amdgcn_mfma_f32_16x16x32_bf16(
                af[ii][ks], bfv[j][ks], acc[ph * 2 + ii][j], 0, 0, 0);
      __builtin_amdgcn_s_setprio(0);
      if (ph == 1) {
        if (t == nt - 2) asm volatile("s_waitcnt vmcnt(0)" ::: "memory");
        else             asm volatile("s_waitcnt vmcnt(3)" ::: "memory");
      }
      QK_BARX();
    }
  }
#undef PAT
#undef PBT
#undef SEGL
#undef ST_A
#undef ST_B0
#undef ST_B123
}

// ---------------------------------------------------------------------------
// Fused QKV GEMM: C[4096,6144] = Xb[4096,2048] x WtQKV[6144,2048]^T.
// Grid 768 (32 M x 24 N) = exactly 3 rounds of 256 CUs.
__global__ __launch_bounds__(512, 2) void gemm_qkv128_kernel(
    const ushort_t* __restrict__ A, const ushort_t* __restrict__ Bt,
    ushort_t* __restrict__ outQ, ushort_t* __restrict__ outK,
    ushort_t* __restrict__ Vt,
    const float* __restrict__ fc, const float* __restrict__ fs) {
  __shared__ char lds[98304];
  const int tid = (int)threadIdx.x;
  const int w = tid >> 6, lane = tid & 63, quad = lane >> 4, l15 = lane & 15;
  const int wr = (w >> 2) * 64, wc = (w & 3) * 64;

  const int wg = ((int)blockIdx.x & 7) * 96 + ((int)blockIdx.x >> 3);
  const size_t bm0 = (size_t)(wg & 31) * 128;
  const size_t bn0 = (size_t)(wg >> 5) * 256;

  f32x4 acc[4][4];
  f32x4 z4 = {0.f, 0.f, 0.f, 0.f};
#pragma unroll
  for (int i = 0; i < 4; ++i)
#pragma unroll
    for (int j = 0; j < 4; ++j) acc[i][j] = z4;

  kloop_128x256(lds, A, Bt, bm0, bn0, acc);

  const int seg = (int)(bn0 >> 11);   // 0=Q, 1=K, 2=V
  if (seg < 2) {
    ushort_t* ob = seg ? outK : outQ;
#pragma unroll
    for (int i = 0; i < 4; ++i)
#pragma unroll
      for (int r = 0; r < 4; ++r) {
        size_t m = bm0 + wr + i * 16 + quad * 4 + r;
        int s = (int)(m & 2047);
#pragma unroll
        for (int j = 0; j < 4; ++j) {
          size_t n = (bn0 + wc + j * 16 + l15) & 2047;
          float v = acc[i][j][r];
          float v2 = dpp_xor1(v);             // RoPE pair partner (col n^1)
          int fi = ((int)n & 127) >> 1;
          float cosv = fc[s * 64 + fi];
          float sinv = fs[s * 64 + fi];
          v = (lane & 1) ? (v2 * sinv + v * cosv) : (v * cosv - v2 * sinv);
          ob[m * 2048 + n] = f2bf(v);
        }
      }
  } else {
    // V segment: per-wave 64(n) x 64(m) transpose patch through LDS.
    char* T = lds + w * 8192;
#pragma unroll
    for (int i = 0; i < 4; ++i)
#pragma unroll
      for (int j = 0; j < 4; ++j) {
        int nn = j * 16 + l15;
        int md0 = i * 8 + quad * 2;
        uint32 p01 = (uint32)f2bf(acc[i][j][0]) | ((uint32)f2bf(acc[i][j][1]) << 16);
        uint32 p23 = (uint32)f2bf(acc[i][j][2]) | ((uint32)f2bf(acc[i][j][3]) << 16);
        *(uint32*)(T + nn * 128 + ((md0 ^ (nn & 31)) * 4)) = p01;
        *(uint32*)(T + nn * 128 + (((md0 + 1) ^ (nn & 31)) * 4)) = p23;
      }
    const int b = (int)(bm0 >> 11);
    const int s0 = (int)(bm0 & 2047) + wr;
    const int n2 = (int)(bn0 & 2047) + wc;
#pragma unroll
    for (int it = 0; it < 32; ++it) {
      int row = it * 2 + (lane >> 5);
      int pp = lane & 31;
      uint32 dv = *(const uint32*)(T + row * 128 + pp * 4);
      int md = pp ^ (row & 31);
      int nloc = n2 + row;
      size_t bh = (size_t)b * 16 + (nloc >> 7);
      *(uint32*)(Vt + (bh * 128 + (size_t)(nloc & 127)) * 2048 + s0 + 2 * md) = dv;
    }
  }
}

// ---------------------------------------------------------------------------
// Output projection: out[4096,2048] fp32 = Ob x WtO^T. Grid 256 = 1 round.
__global__ __launch_bounds__(512, 2) void gemm_wo_kernel(
    const ushort_t* __restrict__ A, const ushort_t* __restrict__ Bt,
    float* __restrict__ out) {
  __shared__ char lds[98304];
  const int tid = (int)threadIdx.x;
  const int w = tid >> 6, lane = tid & 63, quad = lane >> 4, l15 = lane & 15;
  const int wr = (w >> 2) * 64, wc = (w & 3) * 64;

  const int wg = ((int)blockIdx.x & 7) * 32 + ((int)blockIdx.x >> 3);
  const size_t bm0 = (size_t)(wg & 31) * 128;
  const size_t bn0 = (size_t)(wg >> 5) * 256;

  f32x4 acc[4][4];
  f32x4 z4 = {0.f, 0.f, 0.f, 0.f};
#pragma unroll
  for (int i = 0; i < 4; ++i)
#pragma unroll
    for (int j = 0; j < 4; ++j) acc[i][j] = z4;

  kloop_128x256(lds, A, Bt, bm0, bn0, acc);

#pragma unroll
  for (int i = 0; i < 4; ++i)
#pragma unroll
    for (int r = 0; r < 4; ++r) {
      size_t m = bm0 + wr + i * 16 + quad * 4 + r;
#pragma unroll
      for (int j = 0; j < 4; ++j) {
        size_t n = bn0 + wc + j * 16 + l15;
        out[m * 2048 + n] = acc[i][j][r];
      }
    }
}

// ---------------------------------------------------------------------------
// Flash attention, causal, + fused adapter attention.
// R16: KVBLK=128 (two proven 64-wide K/V halves; P buffer reused across the
// two PV half-passes). 2 barriers + 1 vmcnt drain + 8 rowmax chains per 128
// cols (half of R13). No prefetch (R13 proved neutral). LDS 80KB, grid 512.
__global__ __launch_bounds__(256) void flash_kernel(
    const ushort_t* __restrict__ Qb, const ushort_t* __restrict__ Kb,
    const ushort_t* __restrict__ Vt, const ushort_t* __restrict__ akb,
    const ushort_t* __restrict__ avb, const float* __restrict__ gate,
    ushort_t* __restrict__ Ob) {
  __shared__ char ldsK[32768];   // 2 halves x (64 tok x 256B), swz ^(row&15)
  __shared__ char ldsV[32768];   // 2 halves x (128 d x 128B), swz ^(dr&7)
  __shared__ char ldsP[16384];   // 128q x 128B swz (reused per half + epilogue)
  const int tid = threadIdx.x;
  const int w = tid >> 6, lane = tid & 63, quad = lane >> 4, l15 = lane & 15;
  const int idx = blockIdx.x;
  const int p = idx >> 8, c = idx & 255;
  const int u = c >> 4, vv = c & 15;
  const int qt = p ? (15 - u) : u;
  const int hb = (p << 4) | vv;
  const int h = hb >> 1, b = hb & 1;
  const float scale = 0.08838834764831845f;  // 1/sqrt(128)

  bf16x8 ones;
#pragma unroll
  for (int j = 0; j < 8; ++j) ones[j] = (short)0x3F80;

  // Q fragments in registers: 2 m-tiles x 4 d-steps (wave rows w*32..+31)
  bf16x8 qf[2][4];
#pragma unroll
  for (int mt = 0; mt < 2; ++mt) {
    size_t qrow = (size_t)qt * 128 + w * 32 + mt * 16 + l15;
    const ushort_t* base = Qb + ((size_t)b * 2048 + qrow) * 2048 + h * 128 + quad * 8;
#pragma unroll
    for (int ds = 0; ds < 4; ++ds) qf[mt][ds] = *(const bf16x8*)(base + ds * 32);
  }

  f32x4 zero4 = {0.f, 0.f, 0.f, 0.f};
  f32x4 oacc[2][8];
  f32x4 osum[2];
  float mrow[2][4];
#pragma unroll
  for (int mt = 0; mt < 2; ++mt) {
#pragma unroll
    for (int n8 = 0; n8 < 8; ++n8) oacc[mt][n8] = zero4;
    osum[mt] = zero4;
#pragma unroll
    for (int r = 0; r < 4; ++r) mrow[mt][r] = -1e30f;
  }

  for (int kt = 0; kt <= qt; ++kt) {
    // ---- stage 128 k-cols: K halves (8 async16) + V halves (8 async16) ----
#pragma unroll
    for (int hh = 0; hh < 2; ++hh) {
#pragma unroll
      for (int ii = 0; ii < 4; ++ii) {
        int r0 = w * 16 + ii * 4;
        int row = r0 + (lane >> 4);
        int cl = (lane & 15) ^ (row & 15);
        async16(ldsK + hh * 16384 + r0 * 256,
                Kb + ((size_t)b * 2048 + kt * 128 + hh * 64 + row) * 2048 + h * 128 + cl * 8);
      }
    }
#pragma unroll
    for (int hh = 0; hh < 2; ++hh) {
#pragma unroll
      for (int ii = 0; ii < 4; ++ii) {
        int d0 = w * 32 + ii * 8;
        int dr = d0 + (lane >> 3);
        int cl = (lane & 7) ^ (dr & 7);
        async16(ldsV + hh * 16384 + d0 * 128,
                Vt + ((size_t)(b * 16 + h) * 128 + dr) * 2048 + kt * 128 + hh * 64 + cl * 8);
      }
    }
    asm volatile("s_waitcnt vmcnt(0)" ::: "memory");
    QK_BARX();

    // ---- S = Q K^T over 8 nt (128 cols) ----
    f32x4 sacc[2][8];
#pragma unroll
    for (int mt = 0; mt < 2; ++mt)
#pragma unroll
      for (int nt = 0; nt < 8; ++nt) sacc[mt][nt] = zero4;
#pragma unroll
    for (int ds = 0; ds < 4; ++ds) {
      bf16x8 kf[8];
      int ch = ds * 4 + quad;
#pragma unroll
      for (int nt = 0; nt < 8; ++nt) {
        int row = (nt & 3) * 16 + l15;
        kf[nt] = *(const bf16x8*)(ldsK + (nt >> 2) * 16384 + row * 256 +
                                  ((ch ^ (row & 15)) * 16));
      }
#pragma unroll
      for (int mt = 0; mt < 2; ++mt)
#pragma unroll
        for (int nt = 0; nt < 8; ++nt)
          sacc[mt][nt] = __builtin_amdgcn_mfma_f32_16x16x32_bf16(qf[mt][ds], kf[nt], sacc[mt][nt], 0, 0, 0);
    }

    // ---- online softmax over 128 cols (defer-max, THR=8) ----
    const bool domask = (kt == qt);
    float tmax2[2][4];
    float need = 0.f;
#pragma unroll
    for (int mt = 0; mt < 2; ++mt) {
      float tmax[4] = {-1e30f, -1e30f, -1e30f, -1e30f};
      const int qbase = qt * 128 + w * 32 + mt * 16 + quad * 4;
#pragma unroll
      for (int nt = 0; nt < 8; ++nt) {
        int kg = kt * 128 + nt * 16 + l15;
#pragma unroll
        for (int r = 0; r < 4; ++r) {
          float s = sacc[mt][nt][r] * scale;
          if (domask && kg > qbase + r) s = -1e30f;
          sacc[mt][nt][r] = s;
          tmax[r] = fmaxf(tmax[r], s);
        }
      }
#pragma unroll
      for (int r = 0; r < 4; ++r) {
        tmax2[mt][r] = rowmax16(tmax[r]);
        need = fmaxf(need, tmax2[mt][r] - mrow[mt][r]);
      }
    }
    if (__any(need > 8.0f)) {
#pragma unroll
      for (int mt = 0; mt < 2; ++mt) {
        float alpha[4];
#pragma unroll
        for (int r = 0; r < 4; ++r) {
          float mnew = fmaxf(mrow[mt][r], tmax2[mt][r]);
          alpha[r] = __expf(mrow[mt][r] - mnew);
          osum[mt][r] *= alpha[r];
          mrow[mt][r] = mnew;
        }
#pragma unroll
        for (int n8 = 0; n8 < 8; ++n8)
#pragma unroll
          for (int r = 0; r < 4; ++r) oacc[mt][n8][r] *= alpha[r];
      }
    }

    // ---- two PV half-passes (P buffer reused; wave-private rows) ----
#pragma unroll
    for (int hh = 0; hh < 2; ++hh) {
      // P = exp(s - mrow) for cols hh*64..+63; pack pairs via dpp + cvt_pk,
      // even lanes store dwords into swizzled ldsP.
#pragma unroll
      for (int mt = 0; mt < 2; ++mt) {
        uint32 pk[4][4];
#pragma unroll
        for (int nt4 = 0; nt4 < 4; ++nt4)
#pragma unroll
          for (int r = 0; r < 4; ++r) {
            float pv = __expf(sacc[mt][hh * 4 + nt4][r] - mrow[mt][r]);
            float pn = dpp_xor1(pv);
            uint32 d_;
            asm volatile("v_cvt_pk_bf16_f32 %0, %1, %2" : "=v"(d_) : "v"(pv), "v"(pn));
            pk[nt4][r] = d_;
          }
        if (!(lane & 1)) {
#pragma unroll
          for (int nt4 = 0; nt4 < 4; ++nt4)
#pragma unroll
            for (int r = 0; r < 4; ++r) {
              int col = nt4 * 16 + l15;   // even
              int prow = w * 32 + mt * 16 + quad * 4 + r;
              *(uint32*)(ldsP + prow * 128 + (((col >> 3) ^ (prow & 7)) * 16) + (col & 7) * 2) = pk[nt4][r];
            }
        }
      }
      // O += P V ; osum += P 1  (V from half hh)
      const char* bV = ldsV + hh * 16384;
#pragma unroll
      for (int ks = 0; ks < 2; ++ks) {
        int ch = ks * 4 + quad;
        bf16x8 pf[2];
#pragma unroll
        for (int mt = 0; mt < 2; ++mt) {
          int prow = w * 32 + mt * 16 + l15;
          pf[mt] = *(const bf16x8*)(ldsP + prow * 128 + ((ch ^ (prow & 7)) * 16));
        }
#pragma unroll
        for (int mt = 0; mt < 2; ++mt)
          osum[mt] = __builtin_amdgcn_mfma_f32_16x16x32_bf16(pf[mt], ones, osum[mt], 0, 0, 0);
#pragma unroll
        for (int n8 = 0; n8 < 8; ++n8) {
          int dr = n8 * 16 + l15;
          bf16x8 vf = *(const bf16x8*)(bV + dr * 128 + ((ch ^ (dr & 7)) * 16));
#pragma unroll
          for (int mt = 0; mt < 2; ++mt)
            oacc[mt][n8] = __builtin_amdgcn_mfma_f32_16x16x32_bf16(pf[mt], vf, oacc[mt][n8], 0, 0, 0);
        }
      }
    }
    QK_BARX();   // protect K/V LDS before next iteration's staging
  }

  // ---------------- fused adapter epilogue ----------------
  const float g = gate[h];
  {
    int row = w * 32 + (lane >> 1);
    int koff = 16 + (lane & 1) * 8;
    *(uint4*)(ldsP + row * 80 + koff * 2) = make_uint4(0, 0, 0, 0);
  }
  f32x4 sa[2] = {zero4, zero4};
#pragma unroll
  for (int ds = 0; ds < 4; ++ds) {
    bf16x8 kfa = *(const bf16x8*)(akb + ((size_t)h * 16 + l15) * 128 + ds * 32 + quad * 8);
#pragma unroll
    for (int mt = 0; mt < 2; ++mt)
      sa[mt] = __builtin_amdgcn_mfma_f32_16x16x32_bf16(qf[mt][ds], kfa, sa[mt], 0, 0, 0);
  }
#pragma unroll
  for (int mt = 0; mt < 2; ++mt) {
#pragma unroll
    for (int r = 0; r < 4; ++r) {
      float s = sa[mt][r] * scale;
      if (l15 >= 10) s = -1e30f;
      float mx = rowmax16(s);
      float e = __expf(s - mx);
      float sum = rowsum16(e);
      float pv = g * e / sum;
      int row = w * 32 + mt * 16 + quad * 4 + r;
      *(ushort_t*)(ldsP + row * 80 + l15 * 2) = f2bf(pv);
    }
  }
  bf16x8 paf[2];
#pragma unroll
  for (int mt = 0; mt < 2; ++mt)
    paf[mt] = *(const bf16x8*)(ldsP + (w * 32 + mt * 16 + l15) * 80 + quad * 16);

  // normalize main attention
#pragma unroll
  for (int mt = 0; mt < 2; ++mt) {
    float rl[4];
#pragma unroll
    for (int r = 0; r < 4; ++r) rl[r] = 1.f / osum[mt][r];
#pragma unroll
    for (int n8 = 0; n8 < 8; ++n8)
#pragma unroll
      for (int r = 0; r < 4; ++r) oacc[mt][n8][r] *= rl[r];
  }
  // += pa @ avb ; store bf16
#pragma unroll
  for (int n8 = 0; n8 < 8; ++n8) {
    bf16x8 avf = *(const bf16x8*)(avb + ((size_t)h * 128 + n8 * 16 + l15) * 32 + quad * 8);
#pragma unroll
    for (int mt = 0; mt < 2; ++mt)
      oacc[mt][n8] = __builtin_amdgcn_mfma_f32_16x16x32_bf16(paf[mt], avf, oacc[mt][n8], 0, 0, 0);
  }
#pragma unroll
  for (int mt = 0; mt < 2; ++mt) {
    size_t qb0 = (size_t)qt * 128 + w * 32 + mt * 16 + quad * 4;
#pragma unroll
    for (int n8 = 0; n8 < 8; ++n8) {
      size_t col = (size_t)h * 128 + n8 * 16 + l15;
#pragma unroll
      for (int r = 0; r < 4; ++r)
        Ob[((size_t)b * 2048 + qb0 + r) * 2048 + col] = f2bf(oacc[mt][n8][r]);
    }
  }
}

// ---------------------------------------------------------------------------
extern "C" void kernel_launch(void* const* d_in, const int* in_sizes, int n_in,
                              void* d_out, int out_size, void* d_ws, size_t ws_size,
                              hipStream_t stream) {
  (void)in_sizes; (void)n_in; (void)out_size; (void)ws_size;
  const float* x       = (const float*)d_in[0];
  const float* wq      = (const float*)d_in[1];
  const float* wk      = (const float*)d_in[2];
  const float* wv      = (const float*)d_in[3];
  const float* wo      = (const float*)d_in[4];
  const float* adapter = (const float*)d_in[5];
  const float* gate    = (const float*)d_in[6];
  const float* fc      = (const float*)d_in[7];
  const float* fs      = (const float*)d_in[8];

  char* ws = (char*)d_ws;
  ushort_t* Xb   = (ushort_t*)(ws + 0);           // 16 MB (reused as Ob)
  ushort_t* WtQ  = (ushort_t*)(ws + 16777216);    // 8 MB x4 contiguous
  ushort_t* WtO  = (ushort_t*)(ws + 41943040);
  ushort_t* Qb   = (ushort_t*)(ws + 50331648);    // 16 MB
  ushort_t* Kb   = (ushort_t*)(ws + 67108864);    // 16 MB
  ushort_t* Vt   = (ushort_t*)(ws + 83886080);    // 16 MB
  float*    ak   = (float*)   (ws + 100663296);   // 80 KB
  float*    av   = (float*)   (ws + 100745216);   // 80 KB
  ushort_t* akb  = (ushort_t*)(ws + 100827136);   // 64 KB
  ushort_t* avb  = (ushort_t*)(ws + 100892672);   // 128 KB
  ushort_t* Ob   = Xb;

  hipMemsetAsync(ak, 0, 163840, stream);
  prep_kernel<<<8448, 256, 0, stream>>>(x, Xb, wq, wk, wv, wo, WtQ,
                                        adapter, ak, av);
  adapter_pack_kernel<<<256, 256, 0, stream>>>(ak, av, akb, avb);
  gemm_qkv128_kernel<<<dim3(768), 512, 0, stream>>>(Xb, WtQ, Qb, Kb, Vt, fc, fs);
  flash_kernel<<<dim3(512), 256, 0, stream>>>(Qb, Kb, Vt, akb, avb, gate, Ob);
  gemm_wo_kernel<<<dim3(256), 512, 0, stream>>>(Ob, WtO, (float*)d_out);
}

// Round 12
// 400.533 us; speedup vs baseline: 1.1268x; 1.0104x over previous
//
#include <hip/hip_runtime.h>

// ---------------------------------------------------------------------------
// Attention_16698832847178: B=2,S=2048,D=2048,H=16,HD=128,L=10
// R17: (1) flash split-wait: vmcnt(8) after staging (K resident, V in
// flight) -> QK^T + softmax + P-half-0 pack run while V lands; vmcnt(0)+bar
// only before the PV passes. (2) adapter_pack folded into gemm_qkv prologue
// (blocks 0-127 x 512 thr = the 65536 pack threads); dispatch count 6->5.
// Everything else identical to R16 (best verified, 404.7us).
// ---------------------------------------------------------------------------

typedef unsigned short ushort_t;
typedef unsigned int uint32;
typedef __attribute__((ext_vector_type(8))) short bf16x8;   // 8 bf16 = 4 VGPRs
typedef __attribute__((ext_vector_type(4))) float f32x4;

__device__ __forceinline__ void async16(void* lds, const void* g) {
  __builtin_amdgcn_global_load_lds((const __attribute__((address_space(1))) void*)g,
                                   (__attribute__((address_space(3))) void*)lds,
                                   16, 0, 0);
}
__device__ __forceinline__ ushort_t f2bf(float f) {
  uint32 u = __float_as_uint(f);
  u += 0x7FFFu + ((u >> 16) & 1u);   // round-to-nearest-even
  return (ushort_t)(u >> 16);
}
__device__ __forceinline__ float bf2f(ushort_t b) {
  return __uint_as_float(((uint32)b) << 16);
}
// value from lane^1 via DPP quad_perm [1,0,3,2] (VALU, no LDS)
__device__ __forceinline__ float dpp_xor1(float v) {
  return __int_as_float(__builtin_amdgcn_update_dpp(
      0, __float_as_int(v), 0xB1, 0xf, 0xf, true));
}
#define DPP_MAX(t, ctrl) \
  t = fmaxf(t, __int_as_float(__builtin_amdgcn_update_dpp( \
      0, __float_as_int(t), (ctrl), 0xf, 0xf, true)))
#define DPP_ADD(t, ctrl) \
  t += __int_as_float(__builtin_amdgcn_update_dpp( \
      0, __float_as_int(t), (ctrl), 0xf, 0xf, true))
__device__ __forceinline__ float rowmax16(float t) {
  DPP_MAX(t, 0xB1);   // xor 1
  DPP_MAX(t, 0x4E);   // xor 2
  t = fmaxf(t, __int_as_float(__builtin_amdgcn_ds_swizzle(
      __float_as_int(t), 0x101F)));                  // xor 4
  DPP_MAX(t, 0x128);  // row_ror:8 -> xor 8 (halves uniform after xor1/2/4)
  return t;
}
__device__ __forceinline__ float rowsum16(float t) {
  DPP_ADD(t, 0xB1);
  DPP_ADD(t, 0x4E);
  t += __int_as_float(__builtin_amdgcn_ds_swizzle(__float_as_int(t), 0x101F));
  DPP_ADD(t, 0x128);
  return t;
}

// ---------------------------------------------------------------------------
// Merged preprocessing: [0,4096) cast x->bf16; [4096,8192) transpose W;
// [8192,8448) adapter projections (atomic, 256-block layout as before).
__global__ __launch_bounds__(256) void prep_kernel(
    const float* __restrict__ x, ushort_t* __restrict__ Xb,
    const float* __restrict__ w0, const float* __restrict__ w1,
    const float* __restrict__ w2, const float* __restrict__ w3,
    ushort_t* __restrict__ WtBase,
    const float* __restrict__ adapter,
    float* __restrict__ ak, float* __restrict__ av) {
  __shared__ float L[64][65];
  const int bid = (int)blockIdx.x;
  const int t = (int)threadIdx.x;

  if (bid < 4096) {
    // ---- cast x (fp32) -> bf16, 8 elements/thread ----
    size_t i = ((size_t)bid * 256 + t) * 8;
    float4 a = *(const float4*)(x + i);
    float4 b = *(const float4*)(x + i + 4);
    uint4 o;
    o.x = (uint32)f2bf(a.x) | ((uint32)f2bf(a.y) << 16);
    o.y = (uint32)f2bf(a.z) | ((uint32)f2bf(a.w) << 16);
    o.z = (uint32)f2bf(b.x) | ((uint32)f2bf(b.y) << 16);
    o.w = (uint32)f2bf(b.z) | ((uint32)f2bf(b.w) << 16);
    *(uint4*)(Xb + i) = o;
    return;
  }
  if (bid < 8192) {
    // ---- W[k][n] fp32 -> Wt[n][k] bf16 (64x64 tiles) ----
    int c = bid - 4096;
    const int z = c >> 10, rem = c & 1023;
    const int bx = rem & 31, by = rem >> 5;
    const float* W = (z == 0) ? w0 : (z == 1) ? w1 : (z == 2) ? w2 : w3;
    ushort_t* Wt = WtBase + (size_t)z * 4194304;  // 2048*2048
    int tc = t & 63, tr = t >> 6;
    int k0 = bx * 64, n0 = by * 64;
    for (int i = 0; i < 16; ++i) {
      int r = i * 4 + tr;
      L[r][tc] = W[(size_t)(k0 + r) * 2048 + n0 + tc];
    }
    __syncthreads();
    int tr8 = t >> 5, tc2 = t & 31;
    for (int i = 0; i < 8; ++i) {
      int r = i * 8 + tr8;
      uint32 pk = (uint32)f2bf(L[2 * tc2][r]) | ((uint32)f2bf(L[2 * tc2 + 1][r]) << 16);
      *(uint32*)(Wt + (size_t)(n0 + r) * 2048 + k0 + 2 * tc2) = pk;
    }
    return;
  }
  {
    // ---- adapter: ak/av[l][n] = sum_k adapter[l][k] * W[k][n] ----
    int c = bid - 8192;               // [0,256)
    const int z = c >> 7;             // 0=wk, 1=wv
    const int ky = (c >> 3) & 15;     // k-chunk
    const int xx = c & 7;             // n-chunk
    const float* W = z ? w2 : w1;     // wv : wk
    float* out = z ? av : ak;
    float (*As)[128] = (float(*)[128])L;
    int k0 = ky * 128;
    for (int i = t; i < 1280; i += 256)
      As[i >> 7][i & 127] = adapter[(size_t)(i >> 7) * 2048 + k0 + (i & 127)];
    __syncthreads();
    int n = xx * 256 + t;
    float acc[10];
#pragma unroll
    for (int l = 0; l < 10; ++l) acc[l] = 0.f;
    for (int kk = 0; kk < 128; ++kk) {
      float wv_ = W[(size_t)(k0 + kk) * 2048 + n];
#pragma unroll
      for (int l = 0; l < 10; ++l) acc[l] += As[l][kk] * wv_;
    }
#pragma unroll
    for (int l = 0; l < 10; ++l) atomicAdd(&out[l * 2048 + n], acc[l]);
  }
}

#define QK_BARX() asm volatile("s_barrier" ::: "memory")
#define QK_LGKM0() asm volatile("s_waitcnt lgkmcnt(0)" ::: "memory")

// ---------------------------------------------------------------------------
// R8's proven pipelined 128x256 K-loop (A and B in LDS).
__device__ __forceinline__ void kloop_128x256(
    char* lds, const ushort_t* __restrict__ A, const ushort_t* __restrict__ Bt,
    size_t bm0, size_t bn0, f32x4 (&acc)[4][4]) {
  const int tid = (int)threadIdx.x;
  const int w = tid >> 6, lane = tid & 63, quad = lane >> 4, l15 = lane & 15;
  const int wr = (w >> 2) * 64, wc = (w & 3) * 64;
  const int nt = 32;
  char* const pA0 = lds;
  char* const pA1 = lds + 16384;
  char* const pB0 = lds + 32768;
  char* const pB1 = lds + 65536;

#define PAT(T) (((T) & 1) ? pA1 : pA0)
#define PBT(T) (((T) & 1) ? pB1 : pB0)
#define SEGL(OP, LDSB, GROW, T)                                                \
  do {                                                                         \
    int rr_ = w * 8 + (lane >> 3);                                             \
    int cl_ = (lane & 7) ^ (rr_ & 7);                                          \
    async16((LDSB) + w * 1024,                                                 \
            (OP) + ((GROW) + (size_t)rr_) * 2048 + (size_t)((T) * 64 + cl_ * 8)); \
  } while (0)
#define ST_A(T)                                                                \
  do { if ((T) < nt) { SEGL(A, PAT(T), bm0, (T));                              \
                       SEGL(A, PAT(T) + 8192, bm0 + 64, (T)); } } while (0)
#define ST_B0(T)                                                               \
  do { if ((T) < nt) SEGL(Bt, PBT(T), bn0, (T)); } while (0)
#define ST_B123(T)                                                             \
  do { if ((T) < nt) { SEGL(Bt, PBT(T) + 8192,  bn0 + 64,  (T));               \
                       SEGL(Bt, PBT(T) + 16384, bn0 + 128, (T));               \
                       SEGL(Bt, PBT(T) + 24576, bn0 + 192, (T)); } } while (0)

  ST_A(0); ST_B0(0); ST_B123(0); ST_B123(1);
  asm volatile("s_waitcnt vmcnt(3)" ::: "memory");
  QK_BARX();

#pragma unroll 2
  for (int t = 0; t < nt; ++t) {
    const char* pA = PAT(t);
    const char* pB = PBT(t);
    bf16x8 bfv[4][2];
#pragma unroll
    for (int j = 0; j < 4; ++j) {
      int brow = wc + j * 16 + l15;
#pragma unroll
      for (int ks = 0; ks < 2; ++ks)
        bfv[j][ks] = *(const bf16x8*)(pB + brow * 128 +
                                      (((ks * 4 + quad) ^ (brow & 7)) * 16));
    }
#pragma unroll
    for (int ph = 0; ph < 2; ++ph) {
      bf16x8 af[2][2];
#pragma unroll
      for (int ii = 0; ii < 2; ++ii) {
        int arow = wr + (ph * 2 + ii) * 16 + l15;
#pragma unroll
        for (int ks = 0; ks < 2; ++ks)
          af[ii][ks] = *(const bf16x8*)(pA + arow * 128 +
                                        (((ks * 4 + quad) ^ (arow & 7)) * 16));
      }
      if (ph == 0) { ST_A(t + 1); ST_B0(t + 1); }
      else         { ST_B123(t + 2); }
      QK_BARX();
      QK_LGKM0();
      __builtin_amdgcn_s_setprio(1);
#pragma unroll
      for (int ks = 0; ks < 2; ++ks)
#pragma unroll
        for (int ii = 0; ii < 2; ++ii)
#pragma unroll
          for (int j = 0; j < 4; ++j)
            acc[ph * 2 + ii][j] = __builtin_amdgcn_mfma_f32_16x16x32_bf16(
                af[ii][ks], bfv[j][ks], acc[ph * 2 + ii][j], 0, 0, 0);
      __builtin_amdgcn_s_setprio(0);
      if (ph == 1) {
        if (t == nt - 2) asm volatile("s_waitcnt vmcnt(0)" ::: "memory");
        else             asm volatile("s_waitcnt vmcnt(3)" ::: "memory");
      }
      QK_BARX();
    }
  }
#undef PAT
#undef PBT
#undef SEGL
#undef ST_A
#undef ST_B0
#undef ST_B123
}

// ---------------------------------------------------------------------------
// Fused QKV GEMM: C[4096,6144] = Xb[4096,2048] x WtQKV[6144,2048]^T.
// Grid 768 (32 M x 24 N) = exactly 3 rounds of 256 CUs.
// R17: blocks 0-127 also pack ak/av (fp32) -> akb/avb (bf16 fragments) in a
// tiny prologue (512 thr x 128 blk = 65536 = the old pack kernel's threads);
// flash (launched after) reads akb/avb.
__global__ __launch_bounds__(512, 2) void gemm_qkv128_kernel(
    const ushort_t* __restrict__ A, const ushort_t* __restrict__ Bt,
    ushort_t* __restrict__ outQ, ushort_t* __restrict__ outK,
    ushort_t* __restrict__ Vt,
    const float* __restrict__ fc, const float* __restrict__ fs,
    const float* __restrict__ ak, const float* __restrict__ av,
    ushort_t* __restrict__ akb, ushort_t* __restrict__ avb) {
  __shared__ char lds[98304];
  const int tid = (int)threadIdx.x;
  const int w = tid >> 6, lane = tid & 63, quad = lane >> 4, l15 = lane & 15;
  const int wr = (w >> 2) * 64, wc = (w & 3) * 64;

  if ((int)blockIdx.x < 128) {
    int pt = (int)blockIdx.x * 512 + tid;   // [0, 65536)
    if (pt < 32768) {
      int hh = pt >> 11, l = (pt >> 7) & 15, d = pt & 127;
      akb[pt] = (l < 10) ? f2bf(ak[l * 2048 + hh * 128 + d]) : (ushort_t)0;
    }
    int hh = pt >> 12, d = (pt >> 5) & 127, l = pt & 31;
    avb[pt] = (l < 10) ? f2bf(av[l * 2048 + hh * 128 + d]) : (ushort_t)0;
  }

  const int wg = ((int)blockIdx.x & 7) * 96 + ((int)blockIdx.x >> 3);
  const size_t bm0 = (size_t)(wg & 31) * 128;
  const size_t bn0 = (size_t)(wg >> 5) * 256;

  f32x4 acc[4][4];
  f32x4 z4 = {0.f, 0.f, 0.f, 0.f};
#pragma unroll
  for (int i = 0; i < 4; ++i)
#pragma unroll
    for (int j = 0; j < 4; ++j) acc[i][j] = z4;

  kloop_128x256(lds, A, Bt, bm0, bn0, acc);

  const int seg = (int)(bn0 >> 11);   // 0=Q, 1=K, 2=V
  if (seg < 2) {
    ushort_t* ob = seg ? outK : outQ;
#pragma unroll
    for (int i = 0; i < 4; ++i)
#pragma unroll
      for (int r = 0; r < 4; ++r) {
        size_t m = bm0 + wr + i * 16 + quad * 4 + r;
        int s = (int)(m & 2047);
#pragma unroll
        for (int j = 0; j < 4; ++j) {
          size_t n = (bn0 + wc + j * 16 + l15) & 2047;
          float v = acc[i][j][r];
          float v2 = dpp_xor1(v);             // RoPE pair partner (col n^1)
          int fi = ((int)n & 127) >> 1;
          float cosv = fc[s * 64 + fi];
          float sinv = fs[s * 64 + fi];
          v = (lane & 1) ? (v2 * sinv + v * cosv) : (v * cosv - v2 * sinv);
          ob[m * 2048 + n] = f2bf(v);
        }
      }
  } else {
    // V segment: per-wave 64(n) x 64(m) transpose patch through LDS.
    char* T = lds + w * 8192;
#pragma unroll
    for (int i = 0; i < 4; ++i)
#pragma unroll
      for (int j = 0; j < 4; ++j) {
        int nn = j * 16 + l15;
        int md0 = i * 8 + quad * 2;
        uint32 p01 = (uint32)f2bf(acc[i][j][0]) | ((uint32)f2bf(acc[i][j][1]) << 16);
        uint32 p23 = (uint32)f2bf(acc[i][j][2]) | ((uint32)f2bf(acc[i][j][3]) << 16);
        *(uint32*)(T + nn * 128 + ((md0 ^ (nn & 31)) * 4)) = p01;
        *(uint32*)(T + nn * 128 + (((md0 + 1) ^ (nn & 31)) * 4)) = p23;
      }
    const int b = (int)(bm0 >> 11);
    const int s0 = (int)(bm0 & 2047) + wr;
    const int n2 = (int)(bn0 & 2047) + wc;
#pragma unroll
    for (int it = 0; it < 32; ++it) {
      int row = it * 2 + (lane >> 5);
      int pp = lane & 31;
      uint32 dv = *(const uint32*)(T + row * 128 + pp * 4);
      int md = pp ^ (row & 31);
      int nloc = n2 + row;
      size_t bh = (size_t)b * 16 + (nloc >> 7);
      *(uint32*)(Vt + (bh * 128 + (size_t)(nloc & 127)) * 2048 + s0 + 2 * md) = dv;
    }
  }
}

// ---------------------------------------------------------------------------
// Output projection: out[4096,2048] fp32 = Ob x WtO^T. Grid 256 = 1 round.
__global__ __launch_bounds__(512, 2) void gemm_wo_kernel(
    const ushort_t* __restrict__ A, const ushort_t* __restrict__ Bt,
    float* __restrict__ out) {
  __shared__ char lds[98304];
  const int tid = (int)threadIdx.x;
  const int w = tid >> 6, lane = tid & 63, quad = lane >> 4, l15 = lane & 15;
  const int wr = (w >> 2) * 64, wc = (w & 3) * 64;

  const int wg = ((int)blockIdx.x & 7) * 32 + ((int)blockIdx.x >> 3);
  const size_t bm0 = (size_t)(wg & 31) * 128;
  const size_t bn0 = (size_t)(wg >> 5) * 256;

  f32x4 acc[4][4];
  f32x4 z4 = {0.f, 0.f, 0.f, 0.f};
#pragma unroll
  for (int i = 0; i < 4; ++i)
#pragma unroll
    for (int j = 0; j < 4; ++j) acc[i][j] = z4;

  kloop_128x256(lds, A, Bt, bm0, bn0, acc);

#pragma unroll
  for (int i = 0; i < 4; ++i)
#pragma unroll
    for (int r = 0; r < 4; ++r) {
      size_t m = bm0 + wr + i * 16 + quad * 4 + r;
#pragma unroll
      for (int j = 0; j < 4; ++j) {
        size_t n = bn0 + wc + j * 16 + l15;
        out[m * 2048 + n] = acc[i][j][r];
      }
    }
}

// ---------------------------------------------------------------------------
// Flash attention, causal, + fused adapter attention.
// R17: KVBLK=128 with split K/V wait: vmcnt(8) after staging (K resident,
// V still in flight) -> QK^T + softmax + P-half-0 pack run under V latency;
// vmcnt(0)+barrier only before the PV passes. 3 barriers/tile.
__global__ __launch_bounds__(256) void flash_kernel(
    const ushort_t* __restrict__ Qb, const ushort_t* __restrict__ Kb,
    const ushort_t* __restrict__ Vt, const ushort_t* __restrict__ akb,
    const ushort_t* __restrict__ avb, const float* __restrict__ gate,
    ushort_t* __restrict__ Ob) {
  __shared__ char ldsK[32768];   // 2 halves x (64 tok x 256B), swz ^(row&15)
  __shared__ char ldsV[32768];   // 2 halves x (128 d x 128B), swz ^(dr&7)
  __shared__ char ldsP[16384];   // 128q x 128B swz (reused per half + epilogue)
  const int tid = threadIdx.x;
  const int w = tid >> 6, lane = tid & 63, quad = lane >> 4, l15 = lane & 15;
  const int idx = blockIdx.x;
  const int p = idx >> 8, c = idx & 255;
  const int u = c >> 4, vv = c & 15;
  const int qt = p ? (15 - u) : u;
  const int hb = (p << 4) | vv;
  const int h = hb >> 1, b = hb & 1;
  const float scale = 0.08838834764831845f;  // 1/sqrt(128)

  bf16x8 ones;
#pragma unroll
  for (int j = 0; j < 8; ++j) ones[j] = (short)0x3F80;

  // Q fragments in registers: 2 m-tiles x 4 d-steps (wave rows w*32..+31)
  bf16x8 qf[2][4];
#pragma unroll
  for (int mt = 0; mt < 2; ++mt) {
    size_t qrow = (size_t)qt * 128 + w * 32 + mt * 16 + l15;
    const ushort_t* base = Qb + ((size_t)b * 2048 + qrow) * 2048 + h * 128 + quad * 8;
#pragma unroll
    for (int ds = 0; ds < 4; ++ds) qf[mt][ds] = *(const bf16x8*)(base + ds * 32);
  }

  f32x4 zero4 = {0.f, 0.f, 0.f, 0.f};
  f32x4 oacc[2][8];
  f32x4 osum[2];
  float mrow[2][4];
#pragma unroll
  for (int mt = 0; mt < 2; ++mt) {
#pragma unroll
    for (int n8 = 0; n8 < 8; ++n8) oacc[mt][n8] = zero4;
    osum[mt] = zero4;
#pragma unroll
    for (int r = 0; r < 4; ++r) mrow[mt][r] = -1e30f;
  }

// P-half store: exp + dpp/cvt_pk pack + even-lane dword stores into ldsP
#define P_STORE(HH)                                                            \
  do {                                                                         \
    _Pragma("unroll") for (int mt = 0; mt < 2; ++mt) {                         \
      uint32 pk[4][4];                                                         \
      _Pragma("unroll") for (int nt4 = 0; nt4 < 4; ++nt4)                      \
        _Pragma("unroll") for (int r = 0; r < 4; ++r) {                        \
          float pv = __expf(sacc[mt][(HH) * 4 + nt4][r] - mrow[mt][r]);        \
          float pn = dpp_xor1(pv);                                             \
          uint32 d_;                                                           \
          asm volatile("v_cvt_pk_bf16_f32 %0, %1, %2" : "=v"(d_) : "v"(pv), "v"(pn)); \
          pk[nt4][r] = d_;                                                     \
        }                                                                      \
      if (!(lane & 1)) {                                                       \
        _Pragma("unroll") for (int nt4 = 0; nt4 < 4; ++nt4)                    \
          _Pragma("unroll") for (int r = 0; r < 4; ++r) {                      \
            int col = nt4 * 16 + l15;                                          \
            int prow = w * 32 + mt * 16 + quad * 4 + r;                        \
            *(uint32*)(ldsP + prow * 128 + (((col >> 3) ^ (prow & 7)) * 16) +  \
                       (col & 7) * 2) = pk[nt4][r];                            \
          }                                                                    \
      }                                                                        \
    }                                                                          \
  } while (0)
// PV pass over V half HH: O += P V ; osum += P 1
#define PV_PASS(HH)                                                            \
  do {                                                                         \
    const char* bV_ = ldsV + (HH) * 16384;                                     \
    _Pragma("unroll") for (int ks = 0; ks < 2; ++ks) {                         \
      int ch = ks * 4 + quad;                                                  \
      bf16x8 pf[2];                                                            \
      _Pragma("unroll") for (int mt = 0; mt < 2; ++mt) {                       \
        int prow = w * 32 + mt * 16 + l15;                                     \
        pf[mt] = *(const bf16x8*)(ldsP + prow * 128 + ((ch ^ (prow & 7)) * 16)); \
      }                                                                        \
      _Pragma("unroll") for (int mt = 0; mt < 2; ++mt)                         \
        osum[mt] = __builtin_amdgcn_mfma_f32_16x16x32_bf16(pf[mt], ones, osum[mt], 0, 0, 0); \
      _Pragma("unroll") for (int n8 = 0; n8 < 8; ++n8) {                       \
        int dr = n8 * 16 + l15;                                                \
        bf16x8 vf = *(const bf16x8*)(bV_ + dr * 128 + ((ch ^ (dr & 7)) * 16)); \
        _Pragma("unroll") for (int mt = 0; mt < 2; ++mt)                       \
          oacc[mt][n8] = __builtin_amdgcn_mfma_f32_16x16x32_bf16(pf[mt], vf, oacc[mt][n8], 0, 0, 0); \
      }                                                                        \
    }                                                                          \
  } while (0)

  for (int kt = 0; kt <= qt; ++kt) {
    // ---- stage: K halves FIRST (8 async16), then V halves (8 async16) ----
#pragma unroll
    for (int hh = 0; hh < 2; ++hh) {
#pragma unroll
      for (int ii = 0; ii < 4; ++ii) {
        int r0 = w * 16 + ii * 4;
        int row = r0 + (lane >> 4);
        int cl = (lane & 15) ^ (row & 15);
        async16(ldsK + hh * 16384 + r0 * 256,
                Kb + ((size_t)b * 2048 + kt * 128 + hh * 64 + row) * 2048 + h * 128 + cl * 8);
      }
    }
#pragma unroll
    for (int hh = 0; hh < 2; ++hh) {
#pragma unroll
      for (int ii = 0; ii < 4; ++ii) {
        int d0 = w * 32 + ii * 8;
        int dr = d0 + (lane >> 3);
        int cl = (lane & 7) ^ (dr & 7);
        async16(ldsV + hh * 16384 + d0 * 128,
                Vt + ((size_t)(b * 16 + h) * 128 + dr) * 2048 + kt * 128 + hh * 64 + cl * 8);
      }
    }
    asm volatile("s_waitcnt vmcnt(8)" ::: "memory");   // K resident; V in flight
    QK_BARX();

    // ---- S = Q K^T over 8 nt (128 cols) ----
    f32x4 sacc[2][8];
#pragma unroll
    for (int mt = 0; mt < 2; ++mt)
#pragma unroll
      for (int nt = 0; nt < 8; ++nt) sacc[mt][nt] = zero4;
#pragma unroll
    for (int ds = 0; ds < 4; ++ds) {
      bf16x8 kf[8];
      int ch = ds * 4 + quad;
#pragma unroll
      for (int nt = 0; nt < 8; ++nt) {
        int row = (nt & 3) * 16 + l15;
        kf[nt] = *(const bf16x8*)(ldsK + (nt >> 2) * 16384 + row * 256 +
                                  ((ch ^ (row & 15)) * 16));
      }
#pragma unroll
      for (int mt = 0; mt < 2; ++mt)
#pragma unroll
        for (int nt = 0; nt < 8; ++nt)
          sacc[mt][nt] = __builtin_amdgcn_mfma_f32_16x16x32_bf16(qf[mt][ds], kf[nt], sacc[mt][nt], 0, 0, 0);
    }

    // ---- online softmax over 128 cols (defer-max, THR=8) ----
    const bool domask = (kt == qt);
    float tmax2[2][4];
    float need = 0.f;
#pragma unroll
    for (int mt = 0; mt < 2; ++mt) {
      float tmax[4] = {-1e30f, -1e30f, -1e30f, -1e30f};
      const int qbase = qt * 128 + w * 32 + mt * 16 + quad * 4;
#pragma unroll
      for (int nt = 0; nt < 8; ++nt) {
        int kg = kt * 128 + nt * 16 + l15;
#pragma unroll
        for (int r = 0; r < 4; ++r) {
          float s = sacc[mt][nt][r] * scale;
          if (domask && kg > qbase + r) s = -1e30f;
          sacc[mt][nt][r] = s;
          tmax[r] = fmaxf(tmax[r], s);
        }
      }
#pragma unroll
      for (int r = 0; r < 4; ++r) {
        tmax2[mt][r] = rowmax16(tmax[r]);
        need = fmaxf(need, tmax2[mt][r] - mrow[mt][r]);
      }
    }
    if (__any(need > 8.0f)) {
#pragma unroll
      for (int mt = 0; mt < 2; ++mt) {
        float alpha[4];
#pragma unroll
        for (int r = 0; r < 4; ++r) {
          float mnew = fmaxf(mrow[mt][r], tmax2[mt][r]);
          alpha[r] = __expf(mrow[mt][r] - mnew);
          osum[mt][r] *= alpha[r];
          mrow[mt][r] = mnew;
        }
#pragma unroll
        for (int n8 = 0; n8 < 8; ++n8)
#pragma unroll
          for (int r = 0; r < 4; ++r) oacc[mt][n8][r] *= alpha[r];
      }
    }

    // P half 0 packed while V still landing; then wait V and run PV passes.
    P_STORE(0);
    asm volatile("s_waitcnt vmcnt(0)" ::: "memory");   // V resident
    QK_BARX();
    PV_PASS(0);
    P_STORE(1);        // wave-private P rows: no barrier vs PV_PASS(0)
    PV_PASS(1);
    QK_BARX();         // protect K/V LDS before next iteration's staging
  }
#undef P_STORE
#undef PV_PASS

  // ---------------- fused adapter epilogue ----------------
  const float g = gate[h];
  {
    int row = w * 32 + (lane >> 1);
    int koff = 16 + (lane & 1) * 8;
    *(uint4*)(ldsP + row * 80 + koff * 2) = make_uint4(0, 0, 0, 0);
  }
  f32x4 sa[2] = {zero4, zero4};
#pragma unroll
  for (int ds = 0; ds < 4; ++ds) {
    bf16x8 kfa = *(const bf16x8*)(akb + ((size_t)h * 16 + l15) * 128 + ds * 32 + quad * 8);
#pragma unroll
    for (int mt = 0; mt < 2; ++mt)
      sa[mt] = __builtin_amdgcn_mfma_f32_16x16x32_bf16(qf[mt][ds], kfa, sa[mt], 0, 0, 0);
  }
#pragma unroll
  for (int mt = 0; mt < 2; ++mt) {
#pragma unroll
    for (int r = 0; r < 4; ++r) {
      float s = sa[mt][r] * scale;
      if (l15 >= 10) s = -1e30f;
      float mx = rowmax16(s);
      float e = __expf(s - mx);
      float sum = rowsum16(e);
      float pv = g * e / sum;
      int row = w * 32 + mt * 16 + quad * 4 + r;
      *(ushort_t*)(ldsP + row * 80 + l15 * 2) = f2bf(pv);
    }
  }
  bf16x8 paf[2];
#pragma unroll
  for (int mt = 0; mt < 2; ++mt)
    paf[mt] = *(const bf16x8*)(ldsP + (w * 32 + mt * 16 + l15) * 80 + quad * 16);

  // normalize main attention
#pragma unroll
  for (int mt = 0; mt < 2; ++mt) {
    float rl[4];
#pragma unroll
    for (int r = 0; r < 4; ++r) rl[r] = 1.f / osum[mt][r];
#pragma unroll
    for (int n8 = 0; n8 < 8; ++n8)
#pragma unroll
      for (int r = 0; r < 4; ++r) oacc[mt][n8][r] *= rl[r];
  }
  // += pa @ avb ; store bf16
#pragma unroll
  for (int n8 = 0; n8 < 8; ++n8) {
    bf16x8 avf = *(const bf16x8*)(avb + ((size_t)h * 128 + n8 * 16 + l15) * 32 + quad * 8);
#pragma unroll
    for (int mt = 0; mt < 2; ++mt)
      oacc[mt][n8] = __builtin_amdgcn_mfma_f32_16x16x32_bf16(paf[mt], avf, oacc[mt][n8], 0, 0, 0);
  }
#pragma unroll
  for (int mt = 0; mt < 2; ++mt) {
    size_t qb0 = (size_t)qt * 128 + w * 32 + mt * 16 + quad * 4;
#pragma unroll
    for (int n8 = 0; n8 < 8; ++n8) {
      size_t col = (size_t)h * 128 + n8 * 16 + l15;
#pragma unroll
      for (int r = 0; r < 4; ++r)
        Ob[((size_t)b * 2048 + qb0 + r) * 2048 + col] = f2bf(oacc[mt][n8][r]);
    }
  }
}

// ---------------------------------------------------------------------------
extern "C" void kernel_launch(void* const* d_in, const int* in_sizes, int n_in,
                              void* d_out, int out_size, void* d_ws, size_t ws_size,
                              hipStream_t stream) {
  (void)in_sizes; (void)n_in; (void)out_size; (void)ws_size;
  const float* x       = (const float*)d_in[0];
  const float* wq      = (const float*)d_in[1];
  const float* wk      = (const float*)d_in[2];
  const float* wv      = (const float*)d_in[3];
  const float* wo      = (const float*)d_in[4];
  const float* adapter = (const float*)d_in[5];
  const float* gate    = (const float*)d_in[6];
  const float* fc      = (const float*)d_in[7];
  const float* fs      = (const float*)d_in[8];

  char* ws = (char*)d_ws;
  ushort_t* Xb   = (ushort_t*)(ws + 0);           // 16 MB (reused as Ob)
  ushort_t* WtQ  = (ushort_t*)(ws + 16777216);    // 8 MB x4 contiguous
  ushort_t* WtO  = (ushort_t*)(ws + 41943040);
  ushort_t* Qb   = (ushort_t*)(ws + 50331648);    // 16 MB
  ushort_t* Kb   = (ushort_t*)(ws + 67108864);    // 16 MB
  ushort_t* Vt   = (ushort_t*)(ws + 83886080);    // 16 MB
  float*    ak   = (float*)   (ws + 100663296);   // 80 KB
  float*    av   = (float*)   (ws + 100745216);   // 80 KB
  ushort_t* akb  = (ushort_t*)(ws + 100827136);   // 64 KB
  ushort_t* avb  = (ushort_t*)(ws + 100892672);   // 128 KB
  ushort_t* Ob   = Xb;

  hipMemsetAsync(ak, 0, 163840, stream);
  prep_kernel<<<8448, 256, 0, stream>>>(x, Xb, wq, wk, wv, wo, WtQ,
                                        adapter, ak, av);
  gemm_qkv128_kernel<<<dim3(768), 512, 0, stream>>>(Xb, WtQ, Qb, Kb, Vt, fc, fs,
                                                    ak, av, akb, avb);
  flash_kernel<<<dim3(512), 256, 0, stream>>>(Qb, Kb, Vt, akb, avb, gate, Ob);
  gemm_wo_kernel<<<dim3(256), 512, 0, stream>>>(Ob, WtO, (float*)d_out);
}